// Round 13
// baseline (234.956 us; speedup 1.0000x reference)
//
#include <hip/hip_runtime.h>
#include <hip/hip_bf16.h>
#include <cstdint>

#define N_NODES 100000
#define NPAD 100096
#define D 300
#define RD 100
#define NREL 1000
#define E2 200000
#define E1 100000
#define NB 8192
#define NEG 0.2f
#define SCAN_BLKS 391   // ceil(100000/256)
#define NBLKC 782       // ceil(200000/256)
#define NWAVES (NBLKC*4)

typedef __bf16 bf16x8 __attribute__((ext_vector_type(8)));
typedef float f32x4 __attribute__((ext_vector_type(4)));
typedef unsigned short us4 __attribute__((ext_vector_type(4)));
typedef unsigned short us8 __attribute__((ext_vector_type(8)));
typedef unsigned long long ull;

__device__ __forceinline__ float leaky(float x){ return x >= 0.f ? x : NEG*x; }

__device__ __forceinline__ unsigned short f2b(float v){
  unsigned u = __float_as_uint(v);
  unsigned r = u + 0x7FFF + ((u>>16)&1u);
  return (unsigned short)(r>>16);
}
__device__ __forceinline__ float b2f(unsigned short b){
  return __uint_as_float(((unsigned)b) << 16);
}
__device__ __forceinline__ float wred(float v){
  #pragma unroll
  for (int m = 32; m >= 1; m >>= 1) v += __shfl_xor(v, m, 64);
  return v;
}

// ---- init: zero flags, per-level CNT/CUR ----
__global__ void k_init(int* __restrict__ FRO, int* __restrict__ ND2,
                       int* __restrict__ CNTa, int* __restrict__ CURa,
                       int* __restrict__ CNTb, int* __restrict__ CURb){
  int i = blockIdx.x*256 + threadIdx.x;
  if (i < N_NODES){ FRO[i]=0; ND2[i]=0; CNTa[i]=0; CURa[i]=0; CNTb[i]=0; CURb[i]=0; }
}
__global__ void k_flag(const int* __restrict__ ro, int* __restrict__ FRO){
  int o = blockIdx.x*256 + threadIdx.x;
  if (o < NB) FRO[ro[o]] = 1;
}
__global__ void k_need(const int* __restrict__ par1, const int* __restrict__ chi1,
                       const int* __restrict__ roo1, const int* __restrict__ ro,
                       const int* __restrict__ FRO, int* __restrict__ ND2){
  int i = blockIdx.x*256 + threadIdx.x;
  if (i < NB) ND2[ro[i]] = 1;
  if (i < E1){
    int p = par1[i];
    if (FRO[p]){ ND2[p] = 1; ND2[chi1[i]] = 1; ND2[roo1[i]] = 1; }
  }
}

// ---- compaction phase 1: predicates -> wave masks + per-block counts (no atomics) ----
__global__ void k_cnt3(const int* __restrict__ par2, const int* __restrict__ par1,
                       const int* __restrict__ FRO, const int* __restrict__ ND2,
                       ull* __restrict__ MSK, int* __restrict__ BC){
  int i = blockIdx.x*256 + threadIdx.x;
  int lane = threadIdx.x & 63, wid = threadIdx.x >> 6;
  __shared__ int ws[3][4];
  int p2 = (i < E2) && ND2[par2[i]];
  int p1 = (i < E1) && FRO[par1[i]];
  int pn = (i < N_NODES) && ND2[i];
  ull m2 = __ballot(p2), m1 = __ballot(p1), mn = __ballot(pn);
  if (lane == 0){
    int wg = blockIdx.x*4 + wid;
    MSK[0*NWAVES + wg] = m2; ws[0][wid] = __popcll(m2);
    MSK[1*NWAVES + wg] = m1; ws[1][wid] = __popcll(m1);
    MSK[2*NWAVES + wg] = mn; ws[2][wid] = __popcll(mn);
  }
  __syncthreads();
  if (threadIdx.x < 3)
    BC[threadIdx.x*NBLKC + blockIdx.x] =
      ws[threadIdx.x][0]+ws[threadIdx.x][1]+ws[threadIdx.x][2]+ws[threadIdx.x][3];
}

// ---- compaction phase 2: scan block counts (one block per list) ----
__global__ __launch_bounds__(1024) void k_scanblk(const int* __restrict__ BC,
                                                  int* __restrict__ BOFF, int* __restrict__ NLV){
  int l = blockIdx.x;
  __shared__ int ls[1024];
  int v = (threadIdx.x < NBLKC) ? BC[l*NBLKC + threadIdx.x] : 0;
  ls[threadIdx.x] = v;
  __syncthreads();
  for (int off=1; off<1024; off<<=1){
    int t = (threadIdx.x >= off) ? ls[threadIdx.x-off] : 0;
    __syncthreads();
    ls[threadIdx.x] += t;
    __syncthreads();
  }
  if (threadIdx.x < NBLKC) BOFF[l*NBLKC + threadIdx.x] = ls[threadIdx.x] - v;
  if (threadIdx.x == 1023) NLV[l] = ls[1023];
}

// ---- compaction phase 3: write lists from stored masks (deterministic, no atomics) ----
__global__ void k_fill(const ull* __restrict__ MSK, const int* __restrict__ BOFF,
                       int* __restrict__ L2L, int* __restrict__ L1L, int* __restrict__ NDL){
  int i = blockIdx.x*256 + threadIdx.x;
  int lane = threadIdx.x & 63, wid = threadIdx.x >> 6;
  int wg = blockIdx.x*4 + wid;
  __shared__ int ws[3][4];
  ull m2 = MSK[0*NWAVES+wg], m1 = MSK[1*NWAVES+wg], mn = MSK[2*NWAVES+wg];
  if (lane == 0){ ws[0][wid]=__popcll(m2); ws[1][wid]=__popcll(m1); ws[2][wid]=__popcll(mn); }
  __syncthreads();
  int w2=0, w1=0, wn=0;
  #pragma unroll
  for (int k=0;k<4;++k){
    if (k < wid){ w2+=ws[0][k]; w1+=ws[1][k]; wn+=ws[2][k]; }
  }
  ull below = (1ull<<lane) - 1ull;
  if ((m2>>lane)&1ull) L2L[BOFF[0*NBLKC+blockIdx.x] + w2 + __popcll(m2 & below)] = i;
  if ((m1>>lane)&1ull) L1L[BOFF[1*NBLKC+blockIdx.x] + w1 + __popcll(m1 & below)] = i;
  if ((mn>>lane)&1ull) NDL[BOFF[2*NBLKC+blockIdx.x] + wn + __popcll(mn & below)] = i;
}

// ---- fused prep: Bt[112][320], WtB[304][128], Rb[1024][128], MbT[112][128] ----
__global__ void k_prepAll(const float* __restrict__ W, const float* __restrict__ watt,
                          const float* __restrict__ relT, unsigned short* __restrict__ Bt,
                          unsigned short* __restrict__ WtB, unsigned short* __restrict__ Rb,
                          unsigned short* __restrict__ MbT){
  int b = blockIdx.x;
  if (b < 140){
    int u = b*256 + threadIdx.x;
    if (u < 112*320){
      int c = u / 320, k = u % 320;
      float v = 0.f;
      if (k < D){
        if (c < RD) v = W[k*RD + c];
        else if (c < RD+3) v = watt[(c-RD)*D + k];
      }
      Bt[u] = f2b(v);
    }
  } else if (b < 292){
    int u = (b-140)*256 + threadIdx.x;
    if (u < 304*128){
      int dd = u >> 7, k = u & 127;
      float v = (dd < D && k < RD) ? W[dd*RD + k] : 0.f;
      WtB[u] = f2b(v);
    }
  } else if (b < 356){
    int u = (b-292)*256 + threadIdx.x;
    if (u < 1024*16){
      int row = u >> 4, c8 = (u & 15)*8;
      us8 o;
      #pragma unroll
      for (int j=0;j<8;++j){
        int c = c8+j;
        o[j] = (row < NREL && c < RD) ? f2b(relT[row*RD + c]) : (unsigned short)0;
      }
      *(us8*)(Rb + (size_t)row*128 + c8) = o;
    }
  } else {
    int u = (b-356)*256 + threadIdx.x;
    if (u < 112*128){
      int j = u >> 7, i = u & 127;
      float v = 0.f;
      if (i < RD){
        if (j < RD){ float a=0.f; for (int d=0;d<D;++d) a += W[d*RD+i]*W[d*RD+j]; v=a; }
        else if (j == RD){ float a=0.f; for (int d=0;d<D;++d) a += watt[d]*W[d*RD+i]; v=a; }
      }
      MbT[u] = f2b(v);
    }
  }
}

// ---- MFMA relation tables: U = Rb @ WtB^T -> Vh (bf16), RINV, RVW1, RVW2 ----
__global__ __launch_bounds__(256) void k_relmm(const unsigned short* __restrict__ Rb,
    const unsigned short* __restrict__ WtB, const float* __restrict__ watt,
    unsigned short* __restrict__ Vh, float* __restrict__ RINV,
    float* __restrict__ RVW1, float* __restrict__ RVW2){
  int lane = threadIdx.x & 63, wid = threadIdx.x >> 6;
  int r0 = blockIdx.x*64 + wid*16;
  int ep = lane & 15, g = lane >> 4;
  size_t a0 = (size_t)(r0 + ep)*128 + g*8;
  size_t b0 = (size_t)ep*128 + g*8;
  f32x4 acc[19];
  #pragma unroll
  for (int cf=0;cf<19;++cf) acc[cf]=(f32x4){0.f,0.f,0.f,0.f};
  #pragma unroll
  for (int ks=0; ks<4; ++ks){
    bf16x8 af = *(const bf16x8*)(Rb + a0 + ks*32);
    #pragma unroll
    for (int cf=0; cf<19; ++cf){
      bf16x8 bf = *(const bf16x8*)(WtB + b0 + (size_t)cf*16*128 + ks*32);
      acc[cf] = __builtin_amdgcn_mfma_f32_16x16x32_bf16(af, bf, acc[cf], 0, 0, 0);
    }
  }
  float w1v[19], w2v[19];
  #pragma unroll
  for (int cf=0; cf<19; ++cf){
    int col = cf*16+ep;
    bool ok = col < D;
    w1v[cf] = ok ? watt[col] : 0.f;
    w2v[cf] = ok ? watt[D+col] : 0.f;
  }
  #pragma unroll
  for (int reg=0; reg<4; ++reg){
    int row = r0 + g*4 + reg;
    float np = 0.f;
    #pragma unroll
    for (int cf=0; cf<19; ++cf){ float u = acc[cf][reg]; np += u*u; }
    np += __shfl_xor(np,1); np += __shfl_xor(np,2); np += __shfl_xor(np,4); np += __shfl_xor(np,8);
    float iv = 1.f / fmaxf(sqrtf(np), 1e-12f);
    float p1 = 0.f, p2 = 0.f;
    if (row < NREL){
      #pragma unroll
      for (int cf=0; cf<19; ++cf){
        int col = cf*16+ep;
        float v = acc[cf][reg]*iv;
        if (col < D){
          Vh[(size_t)row*D + col] = f2b(v);
          p1 += v*w1v[cf];
          p2 += v*w2v[cf];
        }
      }
    }
    p1 += __shfl_xor(p1,1); p1 += __shfl_xor(p1,2); p1 += __shfl_xor(p1,4); p1 += __shfl_xor(p1,8);
    p2 += __shfl_xor(p2,1); p2 += __shfl_xor(p2,2); p2 += __shfl_xor(p2,4); p2 += __shfl_xor(p2,8);
    if (ep == 0 && row < NREL){
      RINV[row] = iv; RVW1[row] = p1; RVW2[row] = p2;
    }
  }
}

// ---- cast node embeddings to padded bf16 table Xb[NPAD][320] (coalesced) ----
__global__ void k_cast(const float* __restrict__ src, unsigned short* __restrict__ dst){
  int total = NPAD*40;
  for (int u = blockIdx.x*blockDim.x + threadIdx.x; u < total; u += gridDim.x*blockDim.x){
    int row = u/40, c8 = (u%40)*8;
    us8 o;
    if (row < N_NODES && c8 <= 292){
      float4 x = *(const float4*)(src + (size_t)row*D + c8);
      float4 y = *(const float4*)(src + (size_t)row*D + c8 + 4);
      o[0]=f2b(x.x); o[1]=f2b(x.y); o[2]=f2b(x.z); o[3]=f2b(x.w);
      o[4]=f2b(y.x); o[5]=f2b(y.y); o[6]=f2b(y.z); o[7]=f2b(y.w);
    } else {
      #pragma unroll
      for (int j=0;j<8;++j){
        int c = c8+j;
        float v = (row < N_NODES && c < D) ? src[(size_t)row*D + c] : 0.f;
        o[j] = f2b(v);
      }
    }
    *(us8*)(dst + (size_t)row*320 + c8) = o;
  }
}

// ---- MFMA node tables (full, level 2): Gh[n] = bf16(W^T e_n), P[n] ----
__global__ __launch_bounds__(256) void k_nodetab2(const unsigned short* __restrict__ Eb,
    const unsigned short* __restrict__ Bt, unsigned short* __restrict__ Gh, float* __restrict__ P){
  int lane = threadIdx.x & 63, wid = threadIdx.x >> 6;
  int n0 = blockIdx.x*128;
  size_t a0 = (size_t)(n0 + wid*32 + (lane&15))*320 + ((lane>>4)*8);
  size_t b0 = (size_t)(lane&15)*320 + ((lane>>4)*8);
  f32x4 acc[2][7];
  #pragma unroll
  for (int s=0;s<2;++s)
    #pragma unroll
    for (int c=0;c<7;++c) acc[s][c] = (f32x4){0.f,0.f,0.f,0.f};
  for (int ks = 0; ks < 10; ++ks){
    bf16x8 a0f = *(const bf16x8*)(Eb + a0 + ks*32);
    bf16x8 a1f = *(const bf16x8*)(Eb + a0 + 16*320 + ks*32);
    #pragma unroll
    for (int cf=0; cf<7; ++cf){
      bf16x8 bf = *(const bf16x8*)(Bt + b0 + (size_t)cf*16*320 + ks*32);
      acc[0][cf] = __builtin_amdgcn_mfma_f32_16x16x32_bf16(a0f, bf, acc[0][cf], 0, 0, 0);
      acc[1][cf] = __builtin_amdgcn_mfma_f32_16x16x32_bf16(a1f, bf, acc[1][cf], 0, 0, 0);
    }
  }
  int rbase = n0 + wid*32 + ((lane>>4)<<2);
  int cbase = lane & 15;
  #pragma unroll
  for (int sub=0; sub<2; ++sub){
    #pragma unroll
    for (int cf=0; cf<7; ++cf){
      int col = cf*16 + cbase;
      #pragma unroll
      for (int r=0; r<4; ++r){
        int row = rbase + sub*16 + r;
        if (row < N_NODES){
          float v = acc[sub][cf][r];
          if (col < RD) Gh[(size_t)row*RD + col] = f2b(v);
          else if (col < RD+3) P[(size_t)row*4 + (col-RD)] = v;
        }
      }
    }
  }
}

// ---- MFMA node tables (indexed, level 1): rows from NDL, count-capped ----
__global__ __launch_bounds__(256) void k_nodetab2i(const unsigned short* __restrict__ Eb,
    const unsigned short* __restrict__ Bt, const int* __restrict__ NDL, const int* __restrict__ NLV,
    unsigned short* __restrict__ Gh, float* __restrict__ P){
  int nlv = NLV[2];
  int base = blockIdx.x*128;
  if (base >= nlv) return;
  int lane = threadIdx.x & 63, wid = threadIdx.x >> 6;
  int li0 = base + wid*32 + (lane&15);
  int li1 = li0 + 16;
  int row0 = (li0 < nlv) ? NDL[li0] : 0;
  int row1 = (li1 < nlv) ? NDL[li1] : 0;
  size_t a0 = (size_t)row0*320 + ((lane>>4)*8);
  size_t a1 = (size_t)row1*320 + ((lane>>4)*8);
  size_t b0 = (size_t)(lane&15)*320 + ((lane>>4)*8);
  f32x4 acc[2][7];
  #pragma unroll
  for (int s=0;s<2;++s)
    #pragma unroll
    for (int c=0;c<7;++c) acc[s][c] = (f32x4){0.f,0.f,0.f,0.f};
  for (int ks = 0; ks < 10; ++ks){
    bf16x8 a0f = *(const bf16x8*)(Eb + a0 + ks*32);
    bf16x8 a1f = *(const bf16x8*)(Eb + a1 + ks*32);
    #pragma unroll
    for (int cf=0; cf<7; ++cf){
      bf16x8 bf = *(const bf16x8*)(Bt + b0 + (size_t)cf*16*320 + ks*32);
      acc[0][cf] = __builtin_amdgcn_mfma_f32_16x16x32_bf16(a0f, bf, acc[0][cf], 0, 0, 0);
      acc[1][cf] = __builtin_amdgcn_mfma_f32_16x16x32_bf16(a1f, bf, acc[1][cf], 0, 0, 0);
    }
  }
  int lbase = base + wid*32 + ((lane>>4)<<2);
  int cbase = lane & 15;
  #pragma unroll
  for (int sub=0; sub<2; ++sub){
    #pragma unroll
    for (int r=0; r<4; ++r){
      int li = lbase + sub*16 + r;
      if (li >= nlv) continue;
      int row = NDL[li];
      #pragma unroll
      for (int cf=0; cf<7; ++cf){
        int col = cf*16 + cbase;
        float v = acc[sub][cf][r];
        if (col < RD) Gh[(size_t)row*RD + col] = f2b(v);
        else if (col < RD+3) P[(size_t)row*4 + (col-RD)] = v;
      }
    }
  }
}

// ---- level-2 pass 1 (MFMA, compacted): logits + DK + parent histogram ----
__global__ __launch_bounds__(256) void k_pass1_l2c(
    const float* __restrict__ relT, const int* __restrict__ rel2i, const int* __restrict__ relrp2,
    const int* __restrict__ par, const int* __restrict__ chi, const int* __restrict__ roo,
    const unsigned short* __restrict__ Gh, const float* __restrict__ P,
    const unsigned short* __restrict__ MbT,
    const float* __restrict__ RINV, const float* __restrict__ RVW2,
    const int* __restrict__ L2L, const int* __restrict__ NLV,
    float* __restrict__ BBUF, float* __restrict__ DK, int* __restrict__ CNT){
  __shared__ unsigned short Cl[4*16*136];
  int nlv = NLV[0];
  if (blockIdx.x*64 >= nlv) return;
  int lane = threadIdx.x & 63, wid = threadIdx.x >> 6;
  int ep = lane & 15, g = lane >> 4;
  unsigned short* cw = Cl + wid*16*136;
  int idx = blockIdx.x*64 + wid*16 + ep;
  int live = idx < nlv;
  int e = live ? L2L[idx] : 0;
  int rp = par[e];
  int ra = rel2i[e], rb = relrp2[e], rc = chi[e], rr = roo[e];
  const float* rA = relT + (size_t)ra*RD;
  const float* rB = relT + (size_t)rb*RD;
  const unsigned short* gR = Gh + (size_t)rr*RD;
  const unsigned short* gX = Gh + (size_t)rp*RD;
  const unsigned short* gY = Gh + (size_t)rc*RD;
  float dgi = 0.f, dgx = 0.f, dgy = 0.f;
  bf16x8 af[4];
  #pragma unroll
  for (int ks=0; ks<4; ++ks){
    us8 cpack;
    #pragma unroll
    for (int h=0; h<2; ++h){
      int k0 = g*8 + ks*32 + h*4;
      float4 a4 = make_float4(0.f,0.f,0.f,0.f), b4 = a4, grr = a4, grp = a4, gry = a4;
      if (live && k0 <= 96){
        a4  = *(const float4*)(rA + k0);
        b4  = *(const float4*)(rB + k0);
        us4 r4 = *(const us4*)(gR + k0);
        us4 x4 = *(const us4*)(gX + k0);
        us4 y4 = *(const us4*)(gY + k0);
        grr = make_float4(b2f(r4[0]),b2f(r4[1]),b2f(r4[2]),b2f(r4[3]));
        grp = make_float4(b2f(x4[0]),b2f(x4[1]),b2f(x4[2]),b2f(x4[3]));
        gry = make_float4(b2f(y4[0]),b2f(y4[1]),b2f(y4[2]),b2f(y4[3]));
      }
      float4 c4;
      c4.x = a4.x*b4.x; c4.y = a4.y*b4.y; c4.z = a4.z*b4.z; c4.w = a4.w*b4.w;
      dgi += c4.x*grr.x + c4.y*grr.y + c4.z*grr.z + c4.w*grr.w;
      dgx += a4.x*grp.x + a4.y*grp.y + a4.z*grp.z + a4.w*grp.w;
      dgy += a4.x*gry.x + a4.y*gry.y + a4.z*gry.z + a4.w*gry.w;
      cpack[h*4+0]=f2b(c4.x); cpack[h*4+1]=f2b(c4.y); cpack[h*4+2]=f2b(c4.z); cpack[h*4+3]=f2b(c4.w);
    }
    *(us8*)((char*)cw + ep*272 + g*16 + ks*64) = cpack;
    af[ks] = *(bf16x8*)&cpack;
  }
  f32x4 acc[7];
  #pragma unroll
  for (int cf=0; cf<7; ++cf) acc[cf] = (f32x4){0.f,0.f,0.f,0.f};
  #pragma unroll
  for (int cf=0; cf<7; ++cf){
    #pragma unroll
    for (int ks=0; ks<4; ++ks){
      bf16x8 bfr = *(const bf16x8*)(MbT + (size_t)(cf*16+ep)*128 + g*8 + ks*32);
      acc[cf] = __builtin_amdgcn_mfma_f32_16x16x32_bf16(af[ks], bfr, acc[cf], 0, 0, 0);
    }
  }
  dgi += __shfl_xor(dgi, 16); dgi += __shfl_xor(dgi, 32);
  dgx += __shfl_xor(dgx, 16); dgx += __shfl_xor(dgx, 32);
  dgy += __shfl_xor(dgy, 16); dgy += __shfl_xor(dgy, 32);
  __syncthreads();
  #pragma unroll
  for (int r=0; r<4; ++r){
    int row = g*4 + r;
    int src = (lane & 48) | row;
    int livr = __shfl(live, src);
    if (!livr) continue;
    float pr = 0.f;
    #pragma unroll
    for (int cf=0; cf<7; ++cf)
      pr += b2f(cw[row*136 + cf*16 + ep]) * acc[cf][r];
    pr += __shfl_xor(pr, 1); pr += __shfl_xor(pr, 2);
    pr += __shfl_xor(pr, 4); pr += __shfl_xor(pr, 8);
    float dw1r = __shfl(acc[6][r], (lane & 48) | 4);   // t[row][100]
    float dgir = __shfl(dgi, src);
    float dgxr = __shfl(dgx, src);
    float dgyr = __shfl(dgy, src);
    int rar = __shfl(ra, src), rpr = __shfl(rp, src);
    int rcr = __shfl(rc, src), rrr = __shfl(rr, src);
    int er  = __shfl(e, src);
    float invp = 1.f / fmaxf(sqrtf(pr), 1e-12f);
    float rinv = RINV[rar];
    float t1 = (dgir*invp)*(dw1r*invp);
    float t2 = (dgxr*rinv)*RVW2[rar];
    float bb = P[(size_t)rrr*4+0] - 2.f*t1 + P[(size_t)rpr*4+1] - 2.f*t2 + P[(size_t)rcr*4+2];
    bb = leaky(bb);
    if (ep == 0){
      BBUF[er] = bb;
      DK[er] = dgyr * rinv;
      atomicAdd(&CNT[rpr], 1);
    }
  }
}

// ---- level-1 pass 1 (compacted): one wave per live edge ----
__global__ __launch_bounds__(256) void k_pass1_l1c(
    const float* __restrict__ relT, const int* __restrict__ rel1i,
    const int* __restrict__ par, const int* __restrict__ chi, const int* __restrict__ roo,
    const unsigned short* __restrict__ Gh, const float* __restrict__ P,
    const float* __restrict__ RINV, const float* __restrict__ RVW1, const float* __restrict__ RVW2,
    const int* __restrict__ L1L, const int* __restrict__ NLV,
    float* __restrict__ BBUF, float* __restrict__ DK, int* __restrict__ CNT){
  int nlv = NLV[1];
  int j = (blockIdx.x*256 + threadIdx.x) >> 6;
  if (j >= nlv) return;
  int lane = threadIdx.x & 63;
  int e = L1L[j];
  int pp = par[e];
  int r = rel1i[e], cc = chi[e], ii = roo[e];
  const float* rrow = relT + r*RD;
  const unsigned short* gI = Gh + (size_t)ii*RD;
  const unsigned short* gX = Gh + (size_t)pp*RD;
  const unsigned short* gY = Gh + (size_t)cc*RD;
  float ai = rrow[lane]*b2f(gI[lane]);
  float ax = rrow[lane]*b2f(gX[lane]);
  float ay = rrow[lane]*b2f(gY[lane]);
  if (lane < 36){
    ai += rrow[lane+64]*b2f(gI[lane+64]);
    ax += rrow[lane+64]*b2f(gX[lane+64]);
    ay += rrow[lane+64]*b2f(gY[lane+64]);
  }
  float dgi = wred(ai), dgx = wred(ax), dgy = wred(ay);
  if (lane == 0){
    float invn = RINV[r];
    float b = P[(size_t)ii*4+0] - 2.f*(dgi*invn)*RVW1[r]
            + P[(size_t)pp*4+1] - 2.f*(dgx*invn)*RVW2[r]
            + P[(size_t)cc*4+2];
    b = leaky(b);
    BBUF[e] = b;
    DK[e] = dgy * invn;
    atomicAdd(&CNT[pp], 1);
  }
}

// ---- CSR build: exclusive scan over CNT ----
__global__ __launch_bounds__(256) void k_scan_a(const int* __restrict__ CNT,
    int* __restrict__ ROFF, int* __restrict__ PART){
  __shared__ int ls[256];
  int i = blockIdx.x*256 + threadIdx.x;
  int v = (i < N_NODES) ? CNT[i] : 0;
  ls[threadIdx.x] = v;
  __syncthreads();
  for (int off=1; off<256; off<<=1){
    int t = (threadIdx.x >= off) ? ls[threadIdx.x-off] : 0;
    __syncthreads();
    ls[threadIdx.x] += t;
    __syncthreads();
  }
  int incl = ls[threadIdx.x];
  if (i < N_NODES) ROFF[i] = incl - v;
  if (threadIdx.x == 255) PART[blockIdx.x] = incl;
}
__global__ __launch_bounds__(512) void k_scan_b(int* __restrict__ PART){
  __shared__ int ls[512];
  int v = (threadIdx.x < SCAN_BLKS) ? PART[threadIdx.x] : 0;
  ls[threadIdx.x] = v;
  __syncthreads();
  for (int off=1; off<512; off<<=1){
    int t = (threadIdx.x >= off) ? ls[threadIdx.x-off] : 0;
    __syncthreads();
    ls[threadIdx.x] += t;
    __syncthreads();
  }
  if (threadIdx.x < SCAN_BLKS) PART[threadIdx.x] = ls[threadIdx.x] - v;
}
// ---- compacted scatter: iterate live-edge list ----
__global__ void k_scatterc(const int* __restrict__ L, const int* __restrict__ NLV, int which,
                           const int* __restrict__ par, const int* __restrict__ ROFF,
                           const int* __restrict__ PART, int* __restrict__ CUR,
                           int* __restrict__ EIDX){
  int j = blockIdx.x*256 + threadIdx.x;
  if (j >= NLV[which]) return;
  int e = L[j];
  int p = par[e];
  int pos = ROFF[p] + PART[p>>8] + atomicAdd(&CUR[p], 1);
  EIDX[pos] = e;
}

// ---- per-parent softmax + Householder aggregate; DK precomputed ----
__device__ __forceinline__ void agg_bucket(int p, int lane,
    const int* __restrict__ ROFF, const int* __restrict__ PART, const int* __restrict__ CNT,
    const int* __restrict__ EIDX, const float* __restrict__ BBUF, const float* __restrict__ DK,
    const int* __restrict__ chi, const int* __restrict__ relI,
    const unsigned short* __restrict__ Vh, const unsigned short* __restrict__ Xe,
    float acc[5]){
  int cnt = CNT[p];
  if (cnt <= 0) return;
  int base = ROFF[p] + PART[p>>8];
  if (cnt <= 64){
    float bl = (lane < cnt) ? BBUF[EIDX[base+lane]] : -1e30f;
    float m = bl;
    #pragma unroll
    for (int msk=32; msk>=1; msk>>=1) m = fmaxf(m, __shfl_xor(m, msk));
    float el = (lane < cnt) ? __expf(bl - m) : 0.f;
    float s = wred(el);
    float inv = 1.f / fmaxf(s, 1e-10f);
    for (int i=0;i<cnt;++i){
      int eid = EIDX[base+i];
      float a = __shfl(el, i) * inv;
      float s2 = 2.f*DK[eid]*a;
      int y = chi[eid], r = relI[eid];
      const unsigned short* vr = Vh + (size_t)r*D;
      const unsigned short* ey = Xe + (size_t)y*320;
      #pragma unroll
      for (int q=0;q<4;++q){
        int d = lane + 64*q;
        acc[q] += b2f(ey[d])*a - s2*b2f(vr[d]);
      }
      if (lane < 44){
        int d = lane + 256;
        acc[4] += b2f(ey[d])*a - s2*b2f(vr[d]);
      }
    }
  } else {
    float m = -1e30f;
    for (int i=0;i<cnt;++i) m = fmaxf(m, BBUF[EIDX[base+i]]);
    float s = 0.f;
    for (int i=0;i<cnt;++i) s += __expf(BBUF[EIDX[base+i]] - m);
    float inv = 1.f / fmaxf(s, 1e-10f);
    for (int i=0;i<cnt;++i){
      int eid = EIDX[base+i];
      float a = __expf(BBUF[eid]-m)*inv;
      float s2 = 2.f*DK[eid]*a;
      int y = chi[eid], r = relI[eid];
      const unsigned short* vr = Vh + (size_t)r*D;
      const unsigned short* ey = Xe + (size_t)y*320;
      #pragma unroll
      for (int q=0;q<4;++q){
        int d = lane + 64*q;
        acc[q] += b2f(ey[d])*a - s2*b2f(vr[d]);
      }
      if (lane < 44){
        int d = lane + 256;
        acc[4] += b2f(ey[d])*a - s2*b2f(vr[d]);
      }
    }
  }
}

// ---- level-2 (compacted): one wave per needed parent from NDL ----
__global__ __launch_bounds__(256) void k_agg2(const int* __restrict__ ROFF, const int* __restrict__ PART,
    const int* __restrict__ CNT, const int* __restrict__ EIDX,
    const float* __restrict__ BBUF, const float* __restrict__ DK,
    const int* __restrict__ chi, const int* __restrict__ relI,
    const unsigned short* __restrict__ Vh, const unsigned short* __restrict__ Xe,
    const int* __restrict__ NDL, const int* __restrict__ NLV,
    unsigned short* __restrict__ Xo){
  int nlv = NLV[2];
  int idx = (blockIdx.x*256 + threadIdx.x) >> 6;
  if (idx >= nlv) return;
  int lane = threadIdx.x & 63;
  int p = NDL[idx];
  float acc[5] = {0.f,0.f,0.f,0.f,0.f};
  agg_bucket(p, lane, ROFF, PART, CNT, EIDX, BBUF, DK, chi, relI, Vh, Xe, acc);
  const unsigned short* in = Xe + (size_t)p*320;
  unsigned short* op = Xo + (size_t)p*320;
  #pragma unroll
  for (int q=0;q<4;++q){
    int d = lane + 64*q;
    op[d] = f2b(leaky(b2f(in[d]) + acc[q]));
  }
  {
    int d = lane + 256;
    unsigned short o = 0;
    if (lane < 44) o = f2b(leaky(b2f(in[d]) + acc[4]));
    op[d] = o;
  }
}

// ---- level-1: one wave per OUTPUT (8192); writes d_out directly ----
__global__ __launch_bounds__(256) void k_aggout(const int* __restrict__ ro,
    const int* __restrict__ ROFF, const int* __restrict__ PART,
    const int* __restrict__ CNT, const int* __restrict__ EIDX,
    const float* __restrict__ BBUF, const float* __restrict__ DK,
    const int* __restrict__ chi, const int* __restrict__ relI,
    const unsigned short* __restrict__ Vh, const unsigned short* __restrict__ Xe,
    float* __restrict__ out){
  int lane = threadIdx.x & 63;
  int o = (blockIdx.x*256 + threadIdx.x) >> 6;
  if (o >= NB) return;
  int p = ro[o];
  float acc[5] = {0.f,0.f,0.f,0.f,0.f};
  agg_bucket(p, lane, ROFF, PART, CNT, EIDX, BBUF, DK, chi, relI, Vh, Xe, acc);
  const unsigned short* in = Xe + (size_t)p*320;
  float* op = out + (size_t)o*D;
  #pragma unroll
  for (int q=0;q<4;++q){
    int d = lane + 64*q;
    op[d] = leaky(b2f(in[d]) + acc[q]);
  }
  if (lane < 44){
    int d = lane + 256;
    op[d] = leaky(b2f(in[d]) + acc[4]);
  }
}

extern "C" void kernel_launch(void* const* d_in, const int* in_sizes, int n_in,
                              void* d_out, int out_size, void* d_ws, size_t ws_size,
                              hipStream_t stream){
  const float* node = (const float*)d_in[0];
  const float* relT = (const float*)d_in[1];
  const float* W    = (const float*)d_in[2];
  const float* watt = (const float*)d_in[3];
  const int* par2 = (const int*)d_in[4];
  const int* chi2 = (const int*)d_in[5];
  const int* roo2 = (const int*)d_in[6];
  const int* rel2i = (const int*)d_in[7];
  const int* relrp2 = (const int*)d_in[8];
  const int* par1 = (const int*)d_in[9];
  const int* chi1 = (const int*)d_in[10];
  const int* roo1 = (const int*)d_in[11];
  const int* rel1i = (const int*)d_in[12];
  const int* roout = (const int*)d_in[13];

  char* w = (char*)d_ws;
  size_t off = 0;
  auto alloc = [&](size_t bytes)->void*{ void* p = w + off; off += (bytes + 255) & ~(size_t)255; return p; };
  unsigned short* Gh = (unsigned short*)alloc((size_t)N_NODES*RD*2);
  float* P    = (float*)alloc((size_t)N_NODES*4*4);
  unsigned short* Vh = (unsigned short*)alloc((size_t)NREL*D*2);
  float* RINV = (float*)alloc(NREL*4);
  float* RVW1 = (float*)alloc(NREL*4);
  float* RVW2 = (float*)alloc(NREL*4);
  float* BBUF = (float*)alloc((size_t)E2*4);
  float* DKb  = (float*)alloc((size_t)E2*4);
  unsigned short* Xb  = (unsigned short*)alloc((size_t)NPAD*320*2);
  unsigned short* Xb2 = (unsigned short*)alloc((size_t)NPAD*320*2);
  unsigned short* Bt  = (unsigned short*)alloc((size_t)112*320*2);
  unsigned short* MbT = (unsigned short*)alloc((size_t)112*128*2);
  unsigned short* WtB = (unsigned short*)alloc((size_t)304*128*2);
  unsigned short* Rb  = (unsigned short*)alloc((size_t)1024*128*2);
  int* CNTa = (int*)alloc((size_t)N_NODES*4);
  int* CURa = (int*)alloc((size_t)N_NODES*4);
  int* CNTb = (int*)alloc((size_t)N_NODES*4);
  int* CURb = (int*)alloc((size_t)N_NODES*4);
  int* ROFF = (int*)alloc((size_t)N_NODES*4);
  int* PART = (int*)alloc(512*4);
  int* EIDX = (int*)alloc((size_t)E2*4);
  int* FRO  = (int*)alloc((size_t)N_NODES*4);
  int* ND2  = (int*)alloc((size_t)N_NODES*4);
  int* L2L  = (int*)alloc((size_t)E2*4);
  int* L1L  = (int*)alloc((size_t)E1*4);
  int* NDL  = (int*)alloc((size_t)N_NODES*4);
  int* NLV  = (int*)alloc(256);
  ull* MSK  = (ull*)alloc((size_t)3*NWAVES*8);
  int* BC   = (int*)alloc((size_t)3*NBLKC*4);
  int* BOFF = (int*)alloc((size_t)3*NBLKC*4);

  // backward-slice flags + scan-based compaction (index-only dependency, no global atomics)
  k_init<<<dim3(SCAN_BLKS), dim3(256), 0, stream>>>(FRO, ND2, CNTa, CURa, CNTb, CURb);
  k_flag<<<dim3((NB+255)/256), dim3(256), 0, stream>>>(roout, FRO);
  k_need<<<dim3((E1+255)/256), dim3(256), 0, stream>>>(par1, chi1, roo1, roout, FRO, ND2);
  k_cnt3<<<dim3(NBLKC), dim3(256), 0, stream>>>(par2, par1, FRO, ND2, MSK, BC);
  k_scanblk<<<dim3(3), dim3(1024), 0, stream>>>(BC, BOFF, NLV);
  k_fill<<<dim3(NBLKC), dim3(256), 0, stream>>>(MSK, BOFF, L2L, L1L, NDL);

  // constants
  k_prepAll<<<dim3(412), dim3(256), 0, stream>>>(W, watt, relT, Bt, WtB, Rb, MbT);
  k_relmm<<<dim3(16), dim3(256), 0, stream>>>(Rb, WtB, watt, Vh, RINV, RVW1, RVW2);

  // ---------- level 2 ----------
  k_cast<<<dim3(2048), dim3(256), 0, stream>>>(node, Xb);
  k_nodetab2<<<dim3((N_NODES+127)/128), dim3(256), 0, stream>>>(Xb, Bt, Gh, P);
  k_pass1_l2c<<<dim3(E2/64), dim3(256), 0, stream>>>(relT, rel2i, relrp2, par2, chi2, roo2,
                                                     Gh, P, MbT, RINV, RVW2, L2L, NLV, BBUF, DKb, CNTa);
  k_scan_a<<<dim3(SCAN_BLKS), dim3(256), 0, stream>>>(CNTa, ROFF, PART);
  k_scan_b<<<dim3(1), dim3(512), 0, stream>>>(PART);
  k_scatterc<<<dim3((E2+255)/256), dim3(256), 0, stream>>>(L2L, NLV, 0, par2, ROFF, PART, CURa, EIDX);
  k_agg2<<<dim3((N_NODES+3)/4), dim3(256), 0, stream>>>(ROFF, PART, CNTa, EIDX, BBUF, DKb,
                                                        chi2, rel2i, Vh, Xb, NDL, NLV, Xb2);

  // ---------- level 1 ----------
  k_nodetab2i<<<dim3((N_NODES+127)/128), dim3(256), 0, stream>>>(Xb2, Bt, NDL, NLV, Gh, P);
  k_pass1_l1c<<<dim3((E1+3)/4), dim3(256), 0, stream>>>(relT, rel1i, par1, chi1, roo1,
                                                        Gh, P, RINV, RVW1, RVW2, L1L, NLV, BBUF, DKb, CNTb);
  k_scan_a<<<dim3(SCAN_BLKS), dim3(256), 0, stream>>>(CNTb, ROFF, PART);
  k_scan_b<<<dim3(1), dim3(512), 0, stream>>>(PART);
  k_scatterc<<<dim3((E1+255)/256), dim3(256), 0, stream>>>(L1L, NLV, 1, par1, ROFF, PART, CURb, EIDX);
  k_aggout<<<dim3((NB+3)/4), dim3(256), 0, stream>>>(roout, ROFF, PART, CNTb, EIDX, BBUF, DKb,
                                                     chi1, rel1i, Vh, Xb2, (float*)d_out);
}

// Round 14
// 221.164 us; speedup vs baseline: 1.0624x; 1.0624x over previous
//
#include <hip/hip_runtime.h>
#include <hip/hip_bf16.h>
#include <cstdint>

#define N_NODES 100000
#define NPAD 100096
#define D 300
#define RD 100
#define NREL 1000
#define E2 200000
#define E1 100000
#define NB 8192
#define NEG 0.2f
#define SCAN_BLKS 391   // ceil(100000/256)
#define NBLKC 782       // ceil(200000/256)
#define NWAVES (NBLKC*4)

typedef __bf16 bf16x8 __attribute__((ext_vector_type(8)));
typedef float f32x4 __attribute__((ext_vector_type(4)));
typedef unsigned short us4 __attribute__((ext_vector_type(4)));
typedef unsigned short us8 __attribute__((ext_vector_type(8)));
typedef unsigned long long ull;

__device__ __forceinline__ float leaky(float x){ return x >= 0.f ? x : NEG*x; }

__device__ __forceinline__ unsigned short f2b(float v){
  unsigned u = __float_as_uint(v);
  unsigned r = u + 0x7FFF + ((u>>16)&1u);
  return (unsigned short)(r>>16);
}
__device__ __forceinline__ float b2f(unsigned short b){
  return __uint_as_float(((unsigned)b) << 16);
}
__device__ __forceinline__ float wred(float v){
  #pragma unroll
  for (int m = 32; m >= 1; m >>= 1) v += __shfl_xor(v, m, 64);
  return v;
}

// ---- init: zero flags, per-level CNT/CUR ----
__global__ void k_init(int* __restrict__ FRO, int* __restrict__ ND2, int* __restrict__ NDA,
                       int* __restrict__ CNTa, int* __restrict__ CURa,
                       int* __restrict__ CNTb, int* __restrict__ CURb){
  int i = blockIdx.x*256 + threadIdx.x;
  if (i < N_NODES){ FRO[i]=0; ND2[i]=0; NDA[i]=0; CNTa[i]=0; CURa[i]=0; CNTb[i]=0; CURb[i]=0; }
}
__global__ void k_flag(const int* __restrict__ ro, int* __restrict__ FRO){
  int o = blockIdx.x*256 + threadIdx.x;
  if (o < NB) FRO[ro[o]] = 1;
}
__global__ void k_need(const int* __restrict__ par1, const int* __restrict__ chi1,
                       const int* __restrict__ roo1, const int* __restrict__ ro,
                       const int* __restrict__ FRO, int* __restrict__ ND2){
  int i = blockIdx.x*256 + threadIdx.x;
  if (i < NB) ND2[ro[i]] = 1;
  if (i < E1){
    int p = par1[i];
    if (FRO[p]){ ND2[p] = 1; ND2[chi1[i]] = 1; ND2[roo1[i]] = 1; }
  }
}
// ---- NDA = ND2 u {roo2,par2,chi2 of live L2 edges} ----
__global__ void k_need2(const int* __restrict__ par2, const int* __restrict__ chi2,
                        const int* __restrict__ roo2, const int* __restrict__ ND2,
                        int* __restrict__ NDA){
  int i = blockIdx.x*256 + threadIdx.x;
  if (i < N_NODES && ND2[i]) NDA[i] = 1;
  if (i < E2){
    int p = par2[i];
    if (ND2[p]){ NDA[p] = 1; NDA[chi2[i]] = 1; NDA[roo2[i]] = 1; }
  }
}

// ---- compaction phase 1: 4 predicates -> wave masks + per-block counts (no atomics) ----
__global__ void k_cnt4(const int* __restrict__ par2, const int* __restrict__ par1,
                       const int* __restrict__ FRO, const int* __restrict__ ND2,
                       const int* __restrict__ NDA,
                       ull* __restrict__ MSK, int* __restrict__ BC){
  int i = blockIdx.x*256 + threadIdx.x;
  int lane = threadIdx.x & 63, wid = threadIdx.x >> 6;
  __shared__ int ws[4][4];
  int p2 = (i < E2) && ND2[par2[i]];
  int p1 = (i < E1) && FRO[par1[i]];
  int pn = (i < N_NODES) && ND2[i];
  int pa = (i < N_NODES) && NDA[i];
  ull m2 = __ballot(p2), m1 = __ballot(p1), mn = __ballot(pn), ma = __ballot(pa);
  if (lane == 0){
    int wg = blockIdx.x*4 + wid;
    MSK[0*NWAVES + wg] = m2; ws[0][wid] = __popcll(m2);
    MSK[1*NWAVES + wg] = m1; ws[1][wid] = __popcll(m1);
    MSK[2*NWAVES + wg] = mn; ws[2][wid] = __popcll(mn);
    MSK[3*NWAVES + wg] = ma; ws[3][wid] = __popcll(ma);
  }
  __syncthreads();
  if (threadIdx.x < 4)
    BC[threadIdx.x*NBLKC + blockIdx.x] =
      ws[threadIdx.x][0]+ws[threadIdx.x][1]+ws[threadIdx.x][2]+ws[threadIdx.x][3];
}

// ---- compaction phase 2: scan block counts (one block per list) ----
__global__ __launch_bounds__(1024) void k_scanblk(const int* __restrict__ BC,
                                                  int* __restrict__ BOFF, int* __restrict__ NLV){
  int l = blockIdx.x;
  __shared__ int ls[1024];
  int v = (threadIdx.x < NBLKC) ? BC[l*NBLKC + threadIdx.x] : 0;
  ls[threadIdx.x] = v;
  __syncthreads();
  for (int off=1; off<1024; off<<=1){
    int t = (threadIdx.x >= off) ? ls[threadIdx.x-off] : 0;
    __syncthreads();
    ls[threadIdx.x] += t;
    __syncthreads();
  }
  if (threadIdx.x < NBLKC) BOFF[l*NBLKC + threadIdx.x] = ls[threadIdx.x] - v;
  if (threadIdx.x == 1023) NLV[l] = ls[1023];
}

// ---- compaction phase 3: write 4 lists from stored masks (deterministic, no atomics) ----
__global__ void k_fill4(const ull* __restrict__ MSK, const int* __restrict__ BOFF,
                        int* __restrict__ L2L, int* __restrict__ L1L,
                        int* __restrict__ NDL, int* __restrict__ NAL){
  int i = blockIdx.x*256 + threadIdx.x;
  int lane = threadIdx.x & 63, wid = threadIdx.x >> 6;
  int wg = blockIdx.x*4 + wid;
  __shared__ int ws[4][4];
  ull m2 = MSK[0*NWAVES+wg], m1 = MSK[1*NWAVES+wg];
  ull mn = MSK[2*NWAVES+wg], ma = MSK[3*NWAVES+wg];
  if (lane == 0){
    ws[0][wid]=__popcll(m2); ws[1][wid]=__popcll(m1);
    ws[2][wid]=__popcll(mn); ws[3][wid]=__popcll(ma);
  }
  __syncthreads();
  int w2=0, w1=0, wn=0, wa=0;
  #pragma unroll
  for (int k=0;k<4;++k){
    if (k < wid){ w2+=ws[0][k]; w1+=ws[1][k]; wn+=ws[2][k]; wa+=ws[3][k]; }
  }
  ull below = (1ull<<lane) - 1ull;
  if ((m2>>lane)&1ull) L2L[BOFF[0*NBLKC+blockIdx.x] + w2 + __popcll(m2 & below)] = i;
  if ((m1>>lane)&1ull) L1L[BOFF[1*NBLKC+blockIdx.x] + w1 + __popcll(m1 & below)] = i;
  if ((mn>>lane)&1ull) NDL[BOFF[2*NBLKC+blockIdx.x] + wn + __popcll(mn & below)] = i;
  if ((ma>>lane)&1ull) NAL[BOFF[3*NBLKC+blockIdx.x] + wa + __popcll(ma & below)] = i;
}

// ---- fused prep: Bt[112][320], WtB[304][128], Rb[1024][128], MbT[112][128] ----
__global__ void k_prepAll(const float* __restrict__ W, const float* __restrict__ watt,
                          const float* __restrict__ relT, unsigned short* __restrict__ Bt,
                          unsigned short* __restrict__ WtB, unsigned short* __restrict__ Rb,
                          unsigned short* __restrict__ MbT){
  int b = blockIdx.x;
  if (b < 140){
    int u = b*256 + threadIdx.x;
    if (u < 112*320){
      int c = u / 320, k = u % 320;
      float v = 0.f;
      if (k < D){
        if (c < RD) v = W[k*RD + c];
        else if (c < RD+3) v = watt[(c-RD)*D + k];
      }
      Bt[u] = f2b(v);
    }
  } else if (b < 292){
    int u = (b-140)*256 + threadIdx.x;
    if (u < 304*128){
      int dd = u >> 7, k = u & 127;
      float v = (dd < D && k < RD) ? W[dd*RD + k] : 0.f;
      WtB[u] = f2b(v);
    }
  } else if (b < 356){
    int u = (b-292)*256 + threadIdx.x;
    if (u < 1024*16){
      int row = u >> 4, c8 = (u & 15)*8;
      us8 o;
      #pragma unroll
      for (int j=0;j<8;++j){
        int c = c8+j;
        o[j] = (row < NREL && c < RD) ? f2b(relT[row*RD + c]) : (unsigned short)0;
      }
      *(us8*)(Rb + (size_t)row*128 + c8) = o;
    }
  } else {
    int u = (b-356)*256 + threadIdx.x;
    if (u < 112*128){
      int j = u >> 7, i = u & 127;
      float v = 0.f;
      if (i < RD){
        if (j < RD){ float a=0.f; for (int d=0;d<D;++d) a += W[d*RD+i]*W[d*RD+j]; v=a; }
        else if (j == RD){ float a=0.f; for (int d=0;d<D;++d) a += watt[d]*W[d*RD+i]; v=a; }
      }
      MbT[u] = f2b(v);
    }
  }
}

// ---- MFMA relation tables: U = Rb @ WtB^T -> Vh (bf16), RINV, RVW1, RVW2 ----
__global__ __launch_bounds__(256) void k_relmm(const unsigned short* __restrict__ Rb,
    const unsigned short* __restrict__ WtB, const float* __restrict__ watt,
    unsigned short* __restrict__ Vh, float* __restrict__ RINV,
    float* __restrict__ RVW1, float* __restrict__ RVW2){
  int lane = threadIdx.x & 63, wid = threadIdx.x >> 6;
  int r0 = blockIdx.x*64 + wid*16;
  int ep = lane & 15, g = lane >> 4;
  size_t a0 = (size_t)(r0 + ep)*128 + g*8;
  size_t b0 = (size_t)ep*128 + g*8;
  f32x4 acc[19];
  #pragma unroll
  for (int cf=0;cf<19;++cf) acc[cf]=(f32x4){0.f,0.f,0.f,0.f};
  #pragma unroll
  for (int ks=0; ks<4; ++ks){
    bf16x8 af = *(const bf16x8*)(Rb + a0 + ks*32);
    #pragma unroll
    for (int cf=0; cf<19; ++cf){
      bf16x8 bf = *(const bf16x8*)(WtB + b0 + (size_t)cf*16*128 + ks*32);
      acc[cf] = __builtin_amdgcn_mfma_f32_16x16x32_bf16(af, bf, acc[cf], 0, 0, 0);
    }
  }
  float w1v[19], w2v[19];
  #pragma unroll
  for (int cf=0; cf<19; ++cf){
    int col = cf*16+ep;
    bool ok = col < D;
    w1v[cf] = ok ? watt[col] : 0.f;
    w2v[cf] = ok ? watt[D+col] : 0.f;
  }
  #pragma unroll
  for (int reg=0; reg<4; ++reg){
    int row = r0 + g*4 + reg;
    float np = 0.f;
    #pragma unroll
    for (int cf=0; cf<19; ++cf){ float u = acc[cf][reg]; np += u*u; }
    np += __shfl_xor(np,1); np += __shfl_xor(np,2); np += __shfl_xor(np,4); np += __shfl_xor(np,8);
    float iv = 1.f / fmaxf(sqrtf(np), 1e-12f);
    float p1 = 0.f, p2 = 0.f;
    if (row < NREL){
      #pragma unroll
      for (int cf=0; cf<19; ++cf){
        int col = cf*16+ep;
        float v = acc[cf][reg]*iv;
        if (col < D){
          Vh[(size_t)row*D + col] = f2b(v);
          p1 += v*w1v[cf];
          p2 += v*w2v[cf];
        }
      }
    }
    p1 += __shfl_xor(p1,1); p1 += __shfl_xor(p1,2); p1 += __shfl_xor(p1,4); p1 += __shfl_xor(p1,8);
    p2 += __shfl_xor(p2,1); p2 += __shfl_xor(p2,2); p2 += __shfl_xor(p2,4); p2 += __shfl_xor(p2,8);
    if (ep == 0 && row < NREL){
      RINV[row] = iv; RVW1[row] = p1; RVW2[row] = p2;
    }
  }
}

// ---- indexed cast: rows from NAL, coalesced within row ----
__global__ void k_casti(const float* __restrict__ src, const int* __restrict__ NAL,
                        const int* __restrict__ NLV, unsigned short* __restrict__ dst){
  int total = NLV[3]*40;
  for (int u = blockIdx.x*blockDim.x + threadIdx.x; u < total; u += gridDim.x*blockDim.x){
    int row = NAL[u/40];
    int c8 = (u%40)*8;
    us8 o;
    if (c8 <= 292){
      float4 x = *(const float4*)(src + (size_t)row*D + c8);
      float4 y = *(const float4*)(src + (size_t)row*D + c8 + 4);
      o[0]=f2b(x.x); o[1]=f2b(x.y); o[2]=f2b(x.z); o[3]=f2b(x.w);
      o[4]=f2b(y.x); o[5]=f2b(y.y); o[6]=f2b(y.z); o[7]=f2b(y.w);
    } else {
      #pragma unroll
      for (int j=0;j<8;++j){
        int c = c8+j;
        float v = (c < D) ? src[(size_t)row*D + c] : 0.f;
        o[j] = f2b(v);
      }
    }
    *(us8*)(dst + (size_t)row*320 + c8) = o;
  }
}

// ---- MFMA node tables (indexed): rows from LIST[which], count-capped ----
__global__ __launch_bounds__(256) void k_nodetab2i(const unsigned short* __restrict__ Eb,
    const unsigned short* __restrict__ Bt, const int* __restrict__ LST, const int* __restrict__ NLV,
    int which, unsigned short* __restrict__ Gh, float* __restrict__ P){
  int nlv = NLV[which];
  int base = blockIdx.x*128;
  if (base >= nlv) return;
  int lane = threadIdx.x & 63, wid = threadIdx.x >> 6;
  int li0 = base + wid*32 + (lane&15);
  int li1 = li0 + 16;
  int row0 = (li0 < nlv) ? LST[li0] : 0;
  int row1 = (li1 < nlv) ? LST[li1] : 0;
  size_t a0 = (size_t)row0*320 + ((lane>>4)*8);
  size_t a1 = (size_t)row1*320 + ((lane>>4)*8);
  size_t b0 = (size_t)(lane&15)*320 + ((lane>>4)*8);
  f32x4 acc[2][7];
  #pragma unroll
  for (int s=0;s<2;++s)
    #pragma unroll
    for (int c=0;c<7;++c) acc[s][c] = (f32x4){0.f,0.f,0.f,0.f};
  for (int ks = 0; ks < 10; ++ks){
    bf16x8 a0f = *(const bf16x8*)(Eb + a0 + ks*32);
    bf16x8 a1f = *(const bf16x8*)(Eb + a1 + ks*32);
    #pragma unroll
    for (int cf=0; cf<7; ++cf){
      bf16x8 bf = *(const bf16x8*)(Bt + b0 + (size_t)cf*16*320 + ks*32);
      acc[0][cf] = __builtin_amdgcn_mfma_f32_16x16x32_bf16(a0f, bf, acc[0][cf], 0, 0, 0);
      acc[1][cf] = __builtin_amdgcn_mfma_f32_16x16x32_bf16(a1f, bf, acc[1][cf], 0, 0, 0);
    }
  }
  int lbase = base + wid*32 + ((lane>>4)<<2);
  int cbase = lane & 15;
  #pragma unroll
  for (int sub=0; sub<2; ++sub){
    #pragma unroll
    for (int r=0; r<4; ++r){
      int li = lbase + sub*16 + r;
      if (li >= nlv) continue;
      int row = LST[li];
      #pragma unroll
      for (int cf=0; cf<7; ++cf){
        int col = cf*16 + cbase;
        float v = acc[sub][cf][r];
        if (col < RD) Gh[(size_t)row*RD + col] = f2b(v);
        else if (col < RD+3) P[(size_t)row*4 + (col-RD)] = v;
      }
    }
  }
}

// ---- level-2 pass 1 (MFMA, compacted): logits + DK + parent histogram ----
__global__ __launch_bounds__(256) void k_pass1_l2c(
    const float* __restrict__ relT, const int* __restrict__ rel2i, const int* __restrict__ relrp2,
    const int* __restrict__ par, const int* __restrict__ chi, const int* __restrict__ roo,
    const unsigned short* __restrict__ Gh, const float* __restrict__ P,
    const unsigned short* __restrict__ MbT,
    const float* __restrict__ RINV, const float* __restrict__ RVW2,
    const int* __restrict__ L2L, const int* __restrict__ NLV,
    float* __restrict__ BBUF, float* __restrict__ DK, int* __restrict__ CNT){
  __shared__ unsigned short Cl[4*16*136];
  int nlv = NLV[0];
  if (blockIdx.x*64 >= nlv) return;
  int lane = threadIdx.x & 63, wid = threadIdx.x >> 6;
  int ep = lane & 15, g = lane >> 4;
  unsigned short* cw = Cl + wid*16*136;
  int idx = blockIdx.x*64 + wid*16 + ep;
  int live = idx < nlv;
  int e = live ? L2L[idx] : 0;
  int rp = par[e];
  int ra = rel2i[e], rb = relrp2[e], rc = chi[e], rr = roo[e];
  const float* rA = relT + (size_t)ra*RD;
  const float* rB = relT + (size_t)rb*RD;
  const unsigned short* gR = Gh + (size_t)rr*RD;
  const unsigned short* gX = Gh + (size_t)rp*RD;
  const unsigned short* gY = Gh + (size_t)rc*RD;
  float dgi = 0.f, dgx = 0.f, dgy = 0.f;
  bf16x8 af[4];
  #pragma unroll
  for (int ks=0; ks<4; ++ks){
    us8 cpack;
    #pragma unroll
    for (int h=0; h<2; ++h){
      int k0 = g*8 + ks*32 + h*4;
      float4 a4 = make_float4(0.f,0.f,0.f,0.f), b4 = a4, grr = a4, grp = a4, gry = a4;
      if (live && k0 <= 96){
        a4  = *(const float4*)(rA + k0);
        b4  = *(const float4*)(rB + k0);
        us4 r4 = *(const us4*)(gR + k0);
        us4 x4 = *(const us4*)(gX + k0);
        us4 y4 = *(const us4*)(gY + k0);
        grr = make_float4(b2f(r4[0]),b2f(r4[1]),b2f(r4[2]),b2f(r4[3]));
        grp = make_float4(b2f(x4[0]),b2f(x4[1]),b2f(x4[2]),b2f(x4[3]));
        gry = make_float4(b2f(y4[0]),b2f(y4[1]),b2f(y4[2]),b2f(y4[3]));
      }
      float4 c4;
      c4.x = a4.x*b4.x; c4.y = a4.y*b4.y; c4.z = a4.z*b4.z; c4.w = a4.w*b4.w;
      dgi += c4.x*grr.x + c4.y*grr.y + c4.z*grr.z + c4.w*grr.w;
      dgx += a4.x*grp.x + a4.y*grp.y + a4.z*grp.z + a4.w*grp.w;
      dgy += a4.x*gry.x + a4.y*gry.y + a4.z*gry.z + a4.w*gry.w;
      cpack[h*4+0]=f2b(c4.x); cpack[h*4+1]=f2b(c4.y); cpack[h*4+2]=f2b(c4.z); cpack[h*4+3]=f2b(c4.w);
    }
    *(us8*)((char*)cw + ep*272 + g*16 + ks*64) = cpack;
    af[ks] = *(bf16x8*)&cpack;
  }
  f32x4 acc[7];
  #pragma unroll
  for (int cf=0; cf<7; ++cf) acc[cf] = (f32x4){0.f,0.f,0.f,0.f};
  #pragma unroll
  for (int cf=0; cf<7; ++cf){
    #pragma unroll
    for (int ks=0; ks<4; ++ks){
      bf16x8 bfr = *(const bf16x8*)(MbT + (size_t)(cf*16+ep)*128 + g*8 + ks*32);
      acc[cf] = __builtin_amdgcn_mfma_f32_16x16x32_bf16(af[ks], bfr, acc[cf], 0, 0, 0);
    }
  }
  dgi += __shfl_xor(dgi, 16); dgi += __shfl_xor(dgi, 32);
  dgx += __shfl_xor(dgx, 16); dgx += __shfl_xor(dgx, 32);
  dgy += __shfl_xor(dgy, 16); dgy += __shfl_xor(dgy, 32);
  __syncthreads();
  #pragma unroll
  for (int r=0; r<4; ++r){
    int row = g*4 + r;
    int src = (lane & 48) | row;
    int livr = __shfl(live, src);
    if (!livr) continue;
    float pr = 0.f;
    #pragma unroll
    for (int cf=0; cf<7; ++cf)
      pr += b2f(cw[row*136 + cf*16 + ep]) * acc[cf][r];
    pr += __shfl_xor(pr, 1); pr += __shfl_xor(pr, 2);
    pr += __shfl_xor(pr, 4); pr += __shfl_xor(pr, 8);
    float dw1r = __shfl(acc[6][r], (lane & 48) | 4);   // t[row][100]
    float dgir = __shfl(dgi, src);
    float dgxr = __shfl(dgx, src);
    float dgyr = __shfl(dgy, src);
    int rar = __shfl(ra, src), rpr = __shfl(rp, src);
    int rcr = __shfl(rc, src), rrr = __shfl(rr, src);
    int er  = __shfl(e, src);
    float invp = 1.f / fmaxf(sqrtf(pr), 1e-12f);
    float rinv = RINV[rar];
    float t1 = (dgir*invp)*(dw1r*invp);
    float t2 = (dgxr*rinv)*RVW2[rar];
    float bb = P[(size_t)rrr*4+0] - 2.f*t1 + P[(size_t)rpr*4+1] - 2.f*t2 + P[(size_t)rcr*4+2];
    bb = leaky(bb);
    if (ep == 0){
      BBUF[er] = bb;
      DK[er] = dgyr * rinv;
      atomicAdd(&CNT[rpr], 1);
    }
  }
}

// ---- level-1 pass 1 (compacted): one wave per live edge ----
__global__ __launch_bounds__(256) void k_pass1_l1c(
    const float* __restrict__ relT, const int* __restrict__ rel1i,
    const int* __restrict__ par, const int* __restrict__ chi, const int* __restrict__ roo,
    const unsigned short* __restrict__ Gh, const float* __restrict__ P,
    const float* __restrict__ RINV, const float* __restrict__ RVW1, const float* __restrict__ RVW2,
    const int* __restrict__ L1L, const int* __restrict__ NLV,
    float* __restrict__ BBUF, float* __restrict__ DK, int* __restrict__ CNT){
  int nlv = NLV[1];
  int j = (blockIdx.x*256 + threadIdx.x) >> 6;
  if (j >= nlv) return;
  int lane = threadIdx.x & 63;
  int e = L1L[j];
  int pp = par[e];
  int r = rel1i[e], cc = chi[e], ii = roo[e];
  const float* rrow = relT + r*RD;
  const unsigned short* gI = Gh + (size_t)ii*RD;
  const unsigned short* gX = Gh + (size_t)pp*RD;
  const unsigned short* gY = Gh + (size_t)cc*RD;
  float ai = rrow[lane]*b2f(gI[lane]);
  float ax = rrow[lane]*b2f(gX[lane]);
  float ay = rrow[lane]*b2f(gY[lane]);
  if (lane < 36){
    ai += rrow[lane+64]*b2f(gI[lane+64]);
    ax += rrow[lane+64]*b2f(gX[lane+64]);
    ay += rrow[lane+64]*b2f(gY[lane+64]);
  }
  float dgi = wred(ai), dgx = wred(ax), dgy = wred(ay);
  if (lane == 0){
    float invn = RINV[r];
    float b = P[(size_t)ii*4+0] - 2.f*(dgi*invn)*RVW1[r]
            + P[(size_t)pp*4+1] - 2.f*(dgx*invn)*RVW2[r]
            + P[(size_t)cc*4+2];
    b = leaky(b);
    BBUF[e] = b;
    DK[e] = dgy * invn;
    atomicAdd(&CNT[pp], 1);
  }
}

// ---- CSR build: exclusive scan over CNT ----
__global__ __launch_bounds__(256) void k_scan_a(const int* __restrict__ CNT,
    int* __restrict__ ROFF, int* __restrict__ PART){
  __shared__ int ls[256];
  int i = blockIdx.x*256 + threadIdx.x;
  int v = (i < N_NODES) ? CNT[i] : 0;
  ls[threadIdx.x] = v;
  __syncthreads();
  for (int off=1; off<256; off<<=1){
    int t = (threadIdx.x >= off) ? ls[threadIdx.x-off] : 0;
    __syncthreads();
    ls[threadIdx.x] += t;
    __syncthreads();
  }
  int incl = ls[threadIdx.x];
  if (i < N_NODES) ROFF[i] = incl - v;
  if (threadIdx.x == 255) PART[blockIdx.x] = incl;
}
__global__ __launch_bounds__(512) void k_scan_b(int* __restrict__ PART){
  __shared__ int ls[512];
  int v = (threadIdx.x < SCAN_BLKS) ? PART[threadIdx.x] : 0;
  ls[threadIdx.x] = v;
  __syncthreads();
  for (int off=1; off<512; off<<=1){
    int t = (threadIdx.x >= off) ? ls[threadIdx.x-off] : 0;
    __syncthreads();
    ls[threadIdx.x] += t;
    __syncthreads();
  }
  if (threadIdx.x < SCAN_BLKS) PART[threadIdx.x] = ls[threadIdx.x] - v;
}
// ---- compacted scatter: iterate live-edge list ----
__global__ void k_scatterc(const int* __restrict__ L, const int* __restrict__ NLV, int which,
                           const int* __restrict__ par, const int* __restrict__ ROFF,
                           const int* __restrict__ PART, int* __restrict__ CUR,
                           int* __restrict__ EIDX){
  int j = blockIdx.x*256 + threadIdx.x;
  if (j >= NLV[which]) return;
  int e = L[j];
  int p = par[e];
  int pos = ROFF[p] + PART[p>>8] + atomicAdd(&CUR[p], 1);
  EIDX[pos] = e;
}

// ---- per-parent softmax + Householder aggregate; DK precomputed ----
__device__ __forceinline__ void agg_bucket(int p, int lane,
    const int* __restrict__ ROFF, const int* __restrict__ PART, const int* __restrict__ CNT,
    const int* __restrict__ EIDX, const float* __restrict__ BBUF, const float* __restrict__ DK,
    const int* __restrict__ chi, const int* __restrict__ relI,
    const unsigned short* __restrict__ Vh, const unsigned short* __restrict__ Xe,
    float acc[5]){
  int cnt = CNT[p];
  if (cnt <= 0) return;
  int base = ROFF[p] + PART[p>>8];
  if (cnt <= 64){
    float bl = (lane < cnt) ? BBUF[EIDX[base+lane]] : -1e30f;
    float m = bl;
    #pragma unroll
    for (int msk=32; msk>=1; msk>>=1) m = fmaxf(m, __shfl_xor(m, msk));
    float el = (lane < cnt) ? __expf(bl - m) : 0.f;
    float s = wred(el);
    float inv = 1.f / fmaxf(s, 1e-10f);
    for (int i=0;i<cnt;++i){
      int eid = EIDX[base+i];
      float a = __shfl(el, i) * inv;
      float s2 = 2.f*DK[eid]*a;
      int y = chi[eid], r = relI[eid];
      const unsigned short* vr = Vh + (size_t)r*D;
      const unsigned short* ey = Xe + (size_t)y*320;
      #pragma unroll
      for (int q=0;q<4;++q){
        int d = lane + 64*q;
        acc[q] += b2f(ey[d])*a - s2*b2f(vr[d]);
      }
      if (lane < 44){
        int d = lane + 256;
        acc[4] += b2f(ey[d])*a - s2*b2f(vr[d]);
      }
    }
  } else {
    float m = -1e30f;
    for (int i=0;i<cnt;++i) m = fmaxf(m, BBUF[EIDX[base+i]]);
    float s = 0.f;
    for (int i=0;i<cnt;++i) s += __expf(BBUF[EIDX[base+i]] - m);
    float inv = 1.f / fmaxf(s, 1e-10f);
    for (int i=0;i<cnt;++i){
      int eid = EIDX[base+i];
      float a = __expf(BBUF[eid]-m)*inv;
      float s2 = 2.f*DK[eid]*a;
      int y = chi[eid], r = relI[eid];
      const unsigned short* vr = Vh + (size_t)r*D;
      const unsigned short* ey = Xe + (size_t)y*320;
      #pragma unroll
      for (int q=0;q<4;++q){
        int d = lane + 64*q;
        acc[q] += b2f(ey[d])*a - s2*b2f(vr[d]);
      }
      if (lane < 44){
        int d = lane + 256;
        acc[4] += b2f(ey[d])*a - s2*b2f(vr[d]);
      }
    }
  }
}

// ---- level-2 (compacted): one wave per needed parent from NDL ----
__global__ __launch_bounds__(256) void k_agg2(const int* __restrict__ ROFF, const int* __restrict__ PART,
    const int* __restrict__ CNT, const int* __restrict__ EIDX,
    const float* __restrict__ BBUF, const float* __restrict__ DK,
    const int* __restrict__ chi, const int* __restrict__ relI,
    const unsigned short* __restrict__ Vh, const unsigned short* __restrict__ Xe,
    const int* __restrict__ NDL, const int* __restrict__ NLV,
    unsigned short* __restrict__ Xo){
  int nlv = NLV[2];
  int idx = (blockIdx.x*256 + threadIdx.x) >> 6;
  if (idx >= nlv) return;
  int lane = threadIdx.x & 63;
  int p = NDL[idx];
  float acc[5] = {0.f,0.f,0.f,0.f,0.f};
  agg_bucket(p, lane, ROFF, PART, CNT, EIDX, BBUF, DK, chi, relI, Vh, Xe, acc);
  const unsigned short* in = Xe + (size_t)p*320;
  unsigned short* op = Xo + (size_t)p*320;
  #pragma unroll
  for (int q=0;q<4;++q){
    int d = lane + 64*q;
    op[d] = f2b(leaky(b2f(in[d]) + acc[q]));
  }
  {
    int d = lane + 256;
    unsigned short o = 0;
    if (lane < 44) o = f2b(leaky(b2f(in[d]) + acc[4]));
    op[d] = o;
  }
}

// ---- level-1: one wave per OUTPUT (8192); writes d_out directly ----
__global__ __launch_bounds__(256) void k_aggout(const int* __restrict__ ro,
    const int* __restrict__ ROFF, const int* __restrict__ PART,
    const int* __restrict__ CNT, const int* __restrict__ EIDX,
    const float* __restrict__ BBUF, const float* __restrict__ DK,
    const int* __restrict__ chi, const int* __restrict__ relI,
    const unsigned short* __restrict__ Vh, const unsigned short* __restrict__ Xe,
    float* __restrict__ out){
  int lane = threadIdx.x & 63;
  int o = (blockIdx.x*256 + threadIdx.x) >> 6;
  if (o >= NB) return;
  int p = ro[o];
  float acc[5] = {0.f,0.f,0.f,0.f,0.f};
  agg_bucket(p, lane, ROFF, PART, CNT, EIDX, BBUF, DK, chi, relI, Vh, Xe, acc);
  const unsigned short* in = Xe + (size_t)p*320;
  float* op = out + (size_t)o*D;
  #pragma unroll
  for (int q=0;q<4;++q){
    int d = lane + 64*q;
    op[d] = leaky(b2f(in[d]) + acc[q]);
  }
  if (lane < 44){
    int d = lane + 256;
    op[d] = leaky(b2f(in[d]) + acc[4]);
  }
}

extern "C" void kernel_launch(void* const* d_in, const int* in_sizes, int n_in,
                              void* d_out, int out_size, void* d_ws, size_t ws_size,
                              hipStream_t stream){
  const float* node = (const float*)d_in[0];
  const float* relT = (const float*)d_in[1];
  const float* W    = (const float*)d_in[2];
  const float* watt = (const float*)d_in[3];
  const int* par2 = (const int*)d_in[4];
  const int* chi2 = (const int*)d_in[5];
  const int* roo2 = (const int*)d_in[6];
  const int* rel2i = (const int*)d_in[7];
  const int* relrp2 = (const int*)d_in[8];
  const int* par1 = (const int*)d_in[9];
  const int* chi1 = (const int*)d_in[10];
  const int* roo1 = (const int*)d_in[11];
  const int* rel1i = (const int*)d_in[12];
  const int* roout = (const int*)d_in[13];

  char* w = (char*)d_ws;
  size_t off = 0;
  auto alloc = [&](size_t bytes)->void*{ void* p = w + off; off += (bytes + 255) & ~(size_t)255; return p; };
  unsigned short* Gh = (unsigned short*)alloc((size_t)N_NODES*RD*2);
  float* P    = (float*)alloc((size_t)N_NODES*4*4);
  unsigned short* Vh = (unsigned short*)alloc((size_t)NREL*D*2);
  float* RINV = (float*)alloc(NREL*4);
  float* RVW1 = (float*)alloc(NREL*4);
  float* RVW2 = (float*)alloc(NREL*4);
  float* BBUF = (float*)alloc((size_t)E2*4);
  float* DKb  = (float*)alloc((size_t)E2*4);
  unsigned short* Xb  = (unsigned short*)alloc((size_t)NPAD*320*2);
  unsigned short* Xb2 = (unsigned short*)alloc((size_t)NPAD*320*2);
  unsigned short* Bt  = (unsigned short*)alloc((size_t)112*320*2);
  unsigned short* MbT = (unsigned short*)alloc((size_t)112*128*2);
  unsigned short* WtB = (unsigned short*)alloc((size_t)304*128*2);
  unsigned short* Rb  = (unsigned short*)alloc((size_t)1024*128*2);
  int* CNTa = (int*)alloc((size_t)N_NODES*4);
  int* CURa = (int*)alloc((size_t)N_NODES*4);
  int* CNTb = (int*)alloc((size_t)N_NODES*4);
  int* CURb = (int*)alloc((size_t)N_NODES*4);
  int* ROFF = (int*)alloc((size_t)N_NODES*4);
  int* PART = (int*)alloc(512*4);
  int* EIDX = (int*)alloc((size_t)E2*4);
  int* FRO  = (int*)alloc((size_t)N_NODES*4);
  int* ND2  = (int*)alloc((size_t)N_NODES*4);
  int* NDA  = (int*)alloc((size_t)N_NODES*4);
  int* L2L  = (int*)alloc((size_t)E2*4);
  int* L1L  = (int*)alloc((size_t)E1*4);
  int* NDL  = (int*)alloc((size_t)N_NODES*4);
  int* NAL  = (int*)alloc((size_t)N_NODES*4);
  int* NLV  = (int*)alloc(256);
  ull* MSK  = (ull*)alloc((size_t)4*NWAVES*8);
  int* BC   = (int*)alloc((size_t)4*NBLKC*4);
  int* BOFF = (int*)alloc((size_t)4*NBLKC*4);

  // backward-slice flags + scan-based compaction (index-only dependency, no global atomics)
  k_init<<<dim3(SCAN_BLKS), dim3(256), 0, stream>>>(FRO, ND2, NDA, CNTa, CURa, CNTb, CURb);
  k_flag<<<dim3((NB+255)/256), dim3(256), 0, stream>>>(roout, FRO);
  k_need<<<dim3((E1+255)/256), dim3(256), 0, stream>>>(par1, chi1, roo1, roout, FRO, ND2);
  k_need2<<<dim3(NBLKC), dim3(256), 0, stream>>>(par2, chi2, roo2, ND2, NDA);
  k_cnt4<<<dim3(NBLKC), dim3(256), 0, stream>>>(par2, par1, FRO, ND2, NDA, MSK, BC);
  k_scanblk<<<dim3(4), dim3(1024), 0, stream>>>(BC, BOFF, NLV);
  k_fill4<<<dim3(NBLKC), dim3(256), 0, stream>>>(MSK, BOFF, L2L, L1L, NDL, NAL);

  // constants
  k_prepAll<<<dim3(412), dim3(256), 0, stream>>>(W, watt, relT, Bt, WtB, Rb, MbT);
  k_relmm<<<dim3(16), dim3(256), 0, stream>>>(Rb, WtB, watt, Vh, RINV, RVW1, RVW2);

  // ---------- level 2 (restricted to NAL nodes) ----------
  k_casti<<<dim3(2048), dim3(256), 0, stream>>>(node, NAL, NLV, Xb);
  k_nodetab2i<<<dim3((N_NODES+127)/128), dim3(256), 0, stream>>>(Xb, Bt, NAL, NLV, 3, Gh, P);
  k_pass1_l2c<<<dim3(E2/64), dim3(256), 0, stream>>>(relT, rel2i, relrp2, par2, chi2, roo2,
                                                     Gh, P, MbT, RINV, RVW2, L2L, NLV, BBUF, DKb, CNTa);
  k_scan_a<<<dim3(SCAN_BLKS), dim3(256), 0, stream>>>(CNTa, ROFF, PART);
  k_scan_b<<<dim3(1), dim3(512), 0, stream>>>(PART);
  k_scatterc<<<dim3((E2+255)/256), dim3(256), 0, stream>>>(L2L, NLV, 0, par2, ROFF, PART, CURa, EIDX);
  k_agg2<<<dim3((N_NODES+3)/4), dim3(256), 0, stream>>>(ROFF, PART, CNTa, EIDX, BBUF, DKb,
                                                        chi2, rel2i, Vh, Xb, NDL, NLV, Xb2);

  // ---------- level 1 ----------
  k_nodetab2i<<<dim3((N_NODES+127)/128), dim3(256), 0, stream>>>(Xb2, Bt, NDL, NLV, 2, Gh, P);
  k_pass1_l1c<<<dim3((E1+3)/4), dim3(256), 0, stream>>>(relT, rel1i, par1, chi1, roo1,
                                                        Gh, P, RINV, RVW1, RVW2, L1L, NLV, BBUF, DKb, CNTb);
  k_scan_a<<<dim3(SCAN_BLKS), dim3(256), 0, stream>>>(CNTb, ROFF, PART);
  k_scan_b<<<dim3(1), dim3(512), 0, stream>>>(PART);
  k_scatterc<<<dim3((E1+255)/256), dim3(256), 0, stream>>>(L1L, NLV, 1, par1, ROFF, PART, CURb, EIDX);
  k_aggout<<<dim3((NB+3)/4), dim3(256), 0, stream>>>(roout, ROFF, PART, CNTb, EIDX, BBUF, DKb,
                                                     chi1, rel1i, Vh, Xb2, (float*)d_out);
}

// Round 15
// 218.160 us; speedup vs baseline: 1.0770x; 1.0138x over previous
//
#include <hip/hip_runtime.h>
#include <hip/hip_bf16.h>
#include <cstdint>

#define N_NODES 100000
#define NPAD 100096
#define D 300
#define RD 100
#define NREL 1000
#define E2 200000
#define E1 100000
#define NB 8192
#define NEG 0.2f
#define SCAN_BLKS 391   // ceil(100000/256)
#define NBLKC 782       // ceil(200000/256)
#define NWAVES (NBLKC*4)

typedef __bf16 bf16x8 __attribute__((ext_vector_type(8)));
typedef float f32x4 __attribute__((ext_vector_type(4)));
typedef unsigned short us4 __attribute__((ext_vector_type(4)));
typedef unsigned short us8 __attribute__((ext_vector_type(8)));
typedef unsigned long long ull;

__device__ __forceinline__ float leaky(float x){ return x >= 0.f ? x : NEG*x; }

__device__ __forceinline__ unsigned short f2b(float v){
  unsigned u = __float_as_uint(v);
  unsigned r = u + 0x7FFF + ((u>>16)&1u);
  return (unsigned short)(r>>16);
}
__device__ __forceinline__ float b2f(unsigned short b){
  return __uint_as_float(((unsigned)b) << 16);
}
__device__ __forceinline__ float wred(float v){
  #pragma unroll
  for (int m = 32; m >= 1; m >>= 1) v += __shfl_xor(v, m, 64);
  return v;
}

// ---- flag roots: FRO[ro]=1, ND2[ro]=1 ----
__global__ void k_flag(const int* __restrict__ ro, int* __restrict__ FRO, int* __restrict__ ND2){
  int o = blockIdx.x*256 + threadIdx.x;
  if (o < NB){ FRO[ro[o]] = 1; ND2[ro[o]] = 1; }
}
__global__ void k_need(const int* __restrict__ par1, const int* __restrict__ chi1,
                       const int* __restrict__ roo1,
                       const int* __restrict__ FRO, int* __restrict__ ND2){
  int i = blockIdx.x*256 + threadIdx.x;
  if (i < E1){
    int p = par1[i];
    if (FRO[p]){ ND2[p] = 1; ND2[chi1[i]] = 1; ND2[roo1[i]] = 1; }
  }
}
// ---- NDA = ND2 u {roo2,par2,chi2 of live L2 edges} ----
__global__ void k_need2(const int* __restrict__ par2, const int* __restrict__ chi2,
                        const int* __restrict__ roo2, const int* __restrict__ ND2,
                        int* __restrict__ NDA){
  int i = blockIdx.x*256 + threadIdx.x;
  if (i < N_NODES && ND2[i]) NDA[i] = 1;
  if (i < E2){
    int p = par2[i];
    if (ND2[p]){ NDA[p] = 1; NDA[chi2[i]] = 1; NDA[roo2[i]] = 1; }
  }
}

// ---- compaction phase 1: 4 predicates -> wave masks + per-block counts (no atomics) ----
__global__ void k_cnt4(const int* __restrict__ par2, const int* __restrict__ par1,
                       const int* __restrict__ FRO, const int* __restrict__ ND2,
                       const int* __restrict__ NDA,
                       ull* __restrict__ MSK, int* __restrict__ BC){
  int i = blockIdx.x*256 + threadIdx.x;
  int lane = threadIdx.x & 63, wid = threadIdx.x >> 6;
  __shared__ int ws[4][4];
  int p2 = (i < E2) && ND2[par2[i]];
  int p1 = (i < E1) && FRO[par1[i]];
  int pn = (i < N_NODES) && ND2[i];
  int pa = (i < N_NODES) && NDA[i];
  ull m2 = __ballot(p2), m1 = __ballot(p1), mn = __ballot(pn), ma = __ballot(pa);
  if (lane == 0){
    int wg = blockIdx.x*4 + wid;
    MSK[0*NWAVES + wg] = m2; ws[0][wid] = __popcll(m2);
    MSK[1*NWAVES + wg] = m1; ws[1][wid] = __popcll(m1);
    MSK[2*NWAVES + wg] = mn; ws[2][wid] = __popcll(mn);
    MSK[3*NWAVES + wg] = ma; ws[3][wid] = __popcll(ma);
  }
  __syncthreads();
  if (threadIdx.x < 4)
    BC[threadIdx.x*NBLKC + blockIdx.x] =
      ws[threadIdx.x][0]+ws[threadIdx.x][1]+ws[threadIdx.x][2]+ws[threadIdx.x][3];
}

// ---- compaction phase 2: scan block counts (one block per list) ----
__global__ __launch_bounds__(1024) void k_scanblk(const int* __restrict__ BC,
                                                  int* __restrict__ BOFF, int* __restrict__ NLV){
  int l = blockIdx.x;
  __shared__ int ls[1024];
  int v = (threadIdx.x < NBLKC) ? BC[l*NBLKC + threadIdx.x] : 0;
  ls[threadIdx.x] = v;
  __syncthreads();
  for (int off=1; off<1024; off<<=1){
    int t = (threadIdx.x >= off) ? ls[threadIdx.x-off] : 0;
    __syncthreads();
    ls[threadIdx.x] += t;
    __syncthreads();
  }
  if (threadIdx.x < NBLKC) BOFF[l*NBLKC + threadIdx.x] = ls[threadIdx.x] - v;
  if (threadIdx.x == 1023) NLV[l] = ls[1023];
}

// ---- compaction phase 3: write 4 lists from stored masks (deterministic, no atomics) ----
__global__ void k_fill4(const ull* __restrict__ MSK, const int* __restrict__ BOFF,
                        int* __restrict__ L2L, int* __restrict__ L1L,
                        int* __restrict__ NDL, int* __restrict__ NAL){
  int i = blockIdx.x*256 + threadIdx.x;
  int lane = threadIdx.x & 63, wid = threadIdx.x >> 6;
  int wg = blockIdx.x*4 + wid;
  __shared__ int ws[4][4];
  ull m2 = MSK[0*NWAVES+wg], m1 = MSK[1*NWAVES+wg];
  ull mn = MSK[2*NWAVES+wg], ma = MSK[3*NWAVES+wg];
  if (lane == 0){
    ws[0][wid]=__popcll(m2); ws[1][wid]=__popcll(m1);
    ws[2][wid]=__popcll(mn); ws[3][wid]=__popcll(ma);
  }
  __syncthreads();
  int w2=0, w1=0, wn=0, wa=0;
  #pragma unroll
  for (int k=0;k<4;++k){
    if (k < wid){ w2+=ws[0][k]; w1+=ws[1][k]; wn+=ws[2][k]; wa+=ws[3][k]; }
  }
  ull below = (1ull<<lane) - 1ull;
  if ((m2>>lane)&1ull) L2L[BOFF[0*NBLKC+blockIdx.x] + w2 + __popcll(m2 & below)] = i;
  if ((m1>>lane)&1ull) L1L[BOFF[1*NBLKC+blockIdx.x] + w1 + __popcll(m1 & below)] = i;
  if ((mn>>lane)&1ull) NDL[BOFF[2*NBLKC+blockIdx.x] + wn + __popcll(mn & below)] = i;
  if ((ma>>lane)&1ull) NAL[BOFF[3*NBLKC+blockIdx.x] + wa + __popcll(ma & below)] = i;
}

// ---- fused prep: Bt[112][320], WtB[304][128], Rb[1024][128], MbT[112][128] ----
__global__ void k_prepAll(const float* __restrict__ W, const float* __restrict__ watt,
                          const float* __restrict__ relT, unsigned short* __restrict__ Bt,
                          unsigned short* __restrict__ WtB, unsigned short* __restrict__ Rb,
                          unsigned short* __restrict__ MbT){
  int b = blockIdx.x;
  if (b < 140){
    int u = b*256 + threadIdx.x;
    if (u < 112*320){
      int c = u / 320, k = u % 320;
      float v = 0.f;
      if (k < D){
        if (c < RD) v = W[k*RD + c];
        else if (c < RD+3) v = watt[(c-RD)*D + k];
      }
      Bt[u] = f2b(v);
    }
  } else if (b < 292){
    int u = (b-140)*256 + threadIdx.x;
    if (u < 304*128){
      int dd = u >> 7, k = u & 127;
      float v = (dd < D && k < RD) ? W[dd*RD + k] : 0.f;
      WtB[u] = f2b(v);
    }
  } else if (b < 356){
    int u = (b-292)*256 + threadIdx.x;
    if (u < 1024*16){
      int row = u >> 4, c8 = (u & 15)*8;
      us8 o;
      #pragma unroll
      for (int j=0;j<8;++j){
        int c = c8+j;
        o[j] = (row < NREL && c < RD) ? f2b(relT[row*RD + c]) : (unsigned short)0;
      }
      *(us8*)(Rb + (size_t)row*128 + c8) = o;
    }
  } else {
    int u = (b-356)*256 + threadIdx.x;
    if (u < 112*128){
      int j = u >> 7, i = u & 127;
      float v = 0.f;
      if (i < RD){
        if (j < RD){ float a=0.f; for (int d=0;d<D;++d) a += W[d*RD+i]*W[d*RD+j]; v=a; }
        else if (j == RD){ float a=0.f; for (int d=0;d<D;++d) a += watt[d]*W[d*RD+i]; v=a; }
      }
      MbT[u] = f2b(v);
    }
  }
}

// ---- MFMA relation tables: U = Rb @ WtB^T -> Vh (bf16), RINV, RVW1, RVW2 ----
__global__ __launch_bounds__(256) void k_relmm(const unsigned short* __restrict__ Rb,
    const unsigned short* __restrict__ WtB, const float* __restrict__ watt,
    unsigned short* __restrict__ Vh, float* __restrict__ RINV,
    float* __restrict__ RVW1, float* __restrict__ RVW2){
  int lane = threadIdx.x & 63, wid = threadIdx.x >> 6;
  int r0 = blockIdx.x*64 + wid*16;
  int ep = lane & 15, g = lane >> 4;
  size_t a0 = (size_t)(r0 + ep)*128 + g*8;
  size_t b0 = (size_t)ep*128 + g*8;
  f32x4 acc[19];
  #pragma unroll
  for (int cf=0;cf<19;++cf) acc[cf]=(f32x4){0.f,0.f,0.f,0.f};
  #pragma unroll
  for (int ks=0; ks<4; ++ks){
    bf16x8 af = *(const bf16x8*)(Rb + a0 + ks*32);
    #pragma unroll
    for (int cf=0; cf<19; ++cf){
      bf16x8 bf = *(const bf16x8*)(WtB + b0 + (size_t)cf*16*128 + ks*32);
      acc[cf] = __builtin_amdgcn_mfma_f32_16x16x32_bf16(af, bf, acc[cf], 0, 0, 0);
    }
  }
  float w1v[19], w2v[19];
  #pragma unroll
  for (int cf=0; cf<19; ++cf){
    int col = cf*16+ep;
    bool ok = col < D;
    w1v[cf] = ok ? watt[col] : 0.f;
    w2v[cf] = ok ? watt[D+col] : 0.f;
  }
  #pragma unroll
  for (int reg=0; reg<4; ++reg){
    int row = r0 + g*4 + reg;
    float np = 0.f;
    #pragma unroll
    for (int cf=0; cf<19; ++cf){ float u = acc[cf][reg]; np += u*u; }
    np += __shfl_xor(np,1); np += __shfl_xor(np,2); np += __shfl_xor(np,4); np += __shfl_xor(np,8);
    float iv = 1.f / fmaxf(sqrtf(np), 1e-12f);
    float p1 = 0.f, p2 = 0.f;
    if (row < NREL){
      #pragma unroll
      for (int cf=0; cf<19; ++cf){
        int col = cf*16+ep;
        float v = acc[cf][reg]*iv;
        if (col < D){
          Vh[(size_t)row*D + col] = f2b(v);
          p1 += v*w1v[cf];
          p2 += v*w2v[cf];
        }
      }
    }
    p1 += __shfl_xor(p1,1); p1 += __shfl_xor(p1,2); p1 += __shfl_xor(p1,4); p1 += __shfl_xor(p1,8);
    p2 += __shfl_xor(p2,1); p2 += __shfl_xor(p2,2); p2 += __shfl_xor(p2,4); p2 += __shfl_xor(p2,8);
    if (ep == 0 && row < NREL){
      RINV[row] = iv; RVW1[row] = p1; RVW2[row] = p2;
    }
  }
}

// ---- indexed cast: rows from NAL, coalesced within row ----
__global__ void k_casti(const float* __restrict__ src, const int* __restrict__ NAL,
                        const int* __restrict__ NLV, unsigned short* __restrict__ dst){
  int total = NLV[3]*40;
  for (int u = blockIdx.x*blockDim.x + threadIdx.x; u < total; u += gridDim.x*blockDim.x){
    int row = NAL[u/40];
    int c8 = (u%40)*8;
    us8 o;
    if (c8 <= 292){
      float4 x = *(const float4*)(src + (size_t)row*D + c8);
      float4 y = *(const float4*)(src + (size_t)row*D + c8 + 4);
      o[0]=f2b(x.x); o[1]=f2b(x.y); o[2]=f2b(x.z); o[3]=f2b(x.w);
      o[4]=f2b(y.x); o[5]=f2b(y.y); o[6]=f2b(y.z); o[7]=f2b(y.w);
    } else {
      #pragma unroll
      for (int j=0;j<8;++j){
        int c = c8+j;
        float v = (c < D) ? src[(size_t)row*D + c] : 0.f;
        o[j] = f2b(v);
      }
    }
    *(us8*)(dst + (size_t)row*320 + c8) = o;
  }
}

// ---- MFMA node tables (indexed): rows from LIST[which], count-capped ----
__global__ __launch_bounds__(256) void k_nodetab2i(const unsigned short* __restrict__ Eb,
    const unsigned short* __restrict__ Bt, const int* __restrict__ LST, const int* __restrict__ NLV,
    int which, unsigned short* __restrict__ Gh, float* __restrict__ P){
  int nlv = NLV[which];
  int base = blockIdx.x*128;
  if (base >= nlv) return;
  int lane = threadIdx.x & 63, wid = threadIdx.x >> 6;
  int li0 = base + wid*32 + (lane&15);
  int li1 = li0 + 16;
  int row0 = (li0 < nlv) ? LST[li0] : 0;
  int row1 = (li1 < nlv) ? LST[li1] : 0;
  size_t a0 = (size_t)row0*320 + ((lane>>4)*8);
  size_t a1 = (size_t)row1*320 + ((lane>>4)*8);
  size_t b0 = (size_t)(lane&15)*320 + ((lane>>4)*8);
  f32x4 acc[2][7];
  #pragma unroll
  for (int s=0;s<2;++s)
    #pragma unroll
    for (int c=0;c<7;++c) acc[s][c] = (f32x4){0.f,0.f,0.f,0.f};
  for (int ks = 0; ks < 10; ++ks){
    bf16x8 a0f = *(const bf16x8*)(Eb + a0 + ks*32);
    bf16x8 a1f = *(const bf16x8*)(Eb + a1 + ks*32);
    #pragma unroll
    for (int cf=0; cf<7; ++cf){
      bf16x8 bf = *(const bf16x8*)(Bt + b0 + (size_t)cf*16*320 + ks*32);
      acc[0][cf] = __builtin_amdgcn_mfma_f32_16x16x32_bf16(a0f, bf, acc[0][cf], 0, 0, 0);
      acc[1][cf] = __builtin_amdgcn_mfma_f32_16x16x32_bf16(a1f, bf, acc[1][cf], 0, 0, 0);
    }
  }
  int lbase = base + wid*32 + ((lane>>4)<<2);
  int cbase = lane & 15;
  #pragma unroll
  for (int sub=0; sub<2; ++sub){
    #pragma unroll
    for (int r=0; r<4; ++r){
      int li = lbase + sub*16 + r;
      if (li >= nlv) continue;
      int row = LST[li];
      #pragma unroll
      for (int cf=0; cf<7; ++cf){
        int col = cf*16 + cbase;
        float v = acc[sub][cf][r];
        if (col < RD) Gh[(size_t)row*RD + col] = f2b(v);
        else if (col < RD+3) P[(size_t)row*4 + (col-RD)] = v;
      }
    }
  }
}

// ---- level-2 pass 1 (MFMA, compacted): logits + DK + parent histogram ----
__global__ __launch_bounds__(256) void k_pass1_l2c(
    const float* __restrict__ relT, const int* __restrict__ rel2i, const int* __restrict__ relrp2,
    const int* __restrict__ par, const int* __restrict__ chi, const int* __restrict__ roo,
    const unsigned short* __restrict__ Gh, const float* __restrict__ P,
    const unsigned short* __restrict__ MbT,
    const float* __restrict__ RINV, const float* __restrict__ RVW2,
    const int* __restrict__ L2L, const int* __restrict__ NLV,
    float* __restrict__ BBUF, float* __restrict__ DK, int* __restrict__ CNT){
  __shared__ unsigned short Cl[4*16*136];
  int nlv = NLV[0];
  if (blockIdx.x*64 >= nlv) return;
  int lane = threadIdx.x & 63, wid = threadIdx.x >> 6;
  int ep = lane & 15, g = lane >> 4;
  unsigned short* cw = Cl + wid*16*136;
  int idx = blockIdx.x*64 + wid*16 + ep;
  int live = idx < nlv;
  int e = live ? L2L[idx] : 0;
  int rp = par[e];
  int ra = rel2i[e], rb = relrp2[e], rc = chi[e], rr = roo[e];
  const float* rA = relT + (size_t)ra*RD;
  const float* rB = relT + (size_t)rb*RD;
  const unsigned short* gR = Gh + (size_t)rr*RD;
  const unsigned short* gX = Gh + (size_t)rp*RD;
  const unsigned short* gY = Gh + (size_t)rc*RD;
  float dgi = 0.f, dgx = 0.f, dgy = 0.f;
  bf16x8 af[4];
  #pragma unroll
  for (int ks=0; ks<4; ++ks){
    us8 cpack;
    #pragma unroll
    for (int h=0; h<2; ++h){
      int k0 = g*8 + ks*32 + h*4;
      float4 a4 = make_float4(0.f,0.f,0.f,0.f), b4 = a4, grr = a4, grp = a4, gry = a4;
      if (live && k0 <= 96){
        a4  = *(const float4*)(rA + k0);
        b4  = *(const float4*)(rB + k0);
        us4 r4 = *(const us4*)(gR + k0);
        us4 x4 = *(const us4*)(gX + k0);
        us4 y4 = *(const us4*)(gY + k0);
        grr = make_float4(b2f(r4[0]),b2f(r4[1]),b2f(r4[2]),b2f(r4[3]));
        grp = make_float4(b2f(x4[0]),b2f(x4[1]),b2f(x4[2]),b2f(x4[3]));
        gry = make_float4(b2f(y4[0]),b2f(y4[1]),b2f(y4[2]),b2f(y4[3]));
      }
      float4 c4;
      c4.x = a4.x*b4.x; c4.y = a4.y*b4.y; c4.z = a4.z*b4.z; c4.w = a4.w*b4.w;
      dgi += c4.x*grr.x + c4.y*grr.y + c4.z*grr.z + c4.w*grr.w;
      dgx += a4.x*grp.x + a4.y*grp.y + a4.z*grp.z + a4.w*grp.w;
      dgy += a4.x*gry.x + a4.y*gry.y + a4.z*gry.z + a4.w*gry.w;
      cpack[h*4+0]=f2b(c4.x); cpack[h*4+1]=f2b(c4.y); cpack[h*4+2]=f2b(c4.z); cpack[h*4+3]=f2b(c4.w);
    }
    *(us8*)((char*)cw + ep*272 + g*16 + ks*64) = cpack;
    af[ks] = *(bf16x8*)&cpack;
  }
  f32x4 acc[7];
  #pragma unroll
  for (int cf=0; cf<7; ++cf) acc[cf] = (f32x4){0.f,0.f,0.f,0.f};
  #pragma unroll
  for (int cf=0; cf<7; ++cf){
    #pragma unroll
    for (int ks=0; ks<4; ++ks){
      bf16x8 bfr = *(const bf16x8*)(MbT + (size_t)(cf*16+ep)*128 + g*8 + ks*32);
      acc[cf] = __builtin_amdgcn_mfma_f32_16x16x32_bf16(af[ks], bfr, acc[cf], 0, 0, 0);
    }
  }
  dgi += __shfl_xor(dgi, 16); dgi += __shfl_xor(dgi, 32);
  dgx += __shfl_xor(dgx, 16); dgx += __shfl_xor(dgx, 32);
  dgy += __shfl_xor(dgy, 16); dgy += __shfl_xor(dgy, 32);
  __syncthreads();
  #pragma unroll
  for (int r=0; r<4; ++r){
    int row = g*4 + r;
    int src = (lane & 48) | row;
    int livr = __shfl(live, src);
    if (!livr) continue;
    float pr = 0.f;
    #pragma unroll
    for (int cf=0; cf<7; ++cf)
      pr += b2f(cw[row*136 + cf*16 + ep]) * acc[cf][r];
    pr += __shfl_xor(pr, 1); pr += __shfl_xor(pr, 2);
    pr += __shfl_xor(pr, 4); pr += __shfl_xor(pr, 8);
    float dw1r = __shfl(acc[6][r], (lane & 48) | 4);   // t[row][100]
    float dgir = __shfl(dgi, src);
    float dgxr = __shfl(dgx, src);
    float dgyr = __shfl(dgy, src);
    int rar = __shfl(ra, src), rpr = __shfl(rp, src);
    int rcr = __shfl(rc, src), rrr = __shfl(rr, src);
    int er  = __shfl(e, src);
    float invp = 1.f / fmaxf(sqrtf(pr), 1e-12f);
    float rinv = RINV[rar];
    float t1 = (dgir*invp)*(dw1r*invp);
    float t2 = (dgxr*rinv)*RVW2[rar];
    float bb = P[(size_t)rrr*4+0] - 2.f*t1 + P[(size_t)rpr*4+1] - 2.f*t2 + P[(size_t)rcr*4+2];
    bb = leaky(bb);
    if (ep == 0){
      BBUF[er] = bb;
      DK[er] = dgyr * rinv;
      atomicAdd(&CNT[rpr], 1);
    }
  }
}

// ---- level-1 pass 1 (compacted): one wave per live edge ----
__global__ __launch_bounds__(256) void k_pass1_l1c(
    const float* __restrict__ relT, const int* __restrict__ rel1i,
    const int* __restrict__ par, const int* __restrict__ chi, const int* __restrict__ roo,
    const unsigned short* __restrict__ Gh, const float* __restrict__ P,
    const float* __restrict__ RINV, const float* __restrict__ RVW1, const float* __restrict__ RVW2,
    const int* __restrict__ L1L, const int* __restrict__ NLV,
    float* __restrict__ BBUF, float* __restrict__ DK, int* __restrict__ CNT){
  int nlv = NLV[1];
  int j = (blockIdx.x*256 + threadIdx.x) >> 6;
  if (j >= nlv) return;
  int lane = threadIdx.x & 63;
  int e = L1L[j];
  int pp = par[e];
  int r = rel1i[e], cc = chi[e], ii = roo[e];
  const float* rrow = relT + r*RD;
  const unsigned short* gI = Gh + (size_t)ii*RD;
  const unsigned short* gX = Gh + (size_t)pp*RD;
  const unsigned short* gY = Gh + (size_t)cc*RD;
  float ai = rrow[lane]*b2f(gI[lane]);
  float ax = rrow[lane]*b2f(gX[lane]);
  float ay = rrow[lane]*b2f(gY[lane]);
  if (lane < 36){
    ai += rrow[lane+64]*b2f(gI[lane+64]);
    ax += rrow[lane+64]*b2f(gX[lane+64]);
    ay += rrow[lane+64]*b2f(gY[lane+64]);
  }
  float dgi = wred(ai), dgx = wred(ax), dgy = wred(ay);
  if (lane == 0){
    float invn = RINV[r];
    float b = P[(size_t)ii*4+0] - 2.f*(dgi*invn)*RVW1[r]
            + P[(size_t)pp*4+1] - 2.f*(dgx*invn)*RVW2[r]
            + P[(size_t)cc*4+2];
    b = leaky(b);
    BBUF[e] = b;
    DK[e] = dgy * invn;
    atomicAdd(&CNT[pp], 1);
  }
}

// ---- CSR build: exclusive scan over CNT ----
__global__ __launch_bounds__(256) void k_scan_a(const int* __restrict__ CNT,
    int* __restrict__ ROFF, int* __restrict__ PART){
  __shared__ int ls[256];
  int i = blockIdx.x*256 + threadIdx.x;
  int v = (i < N_NODES) ? CNT[i] : 0;
  ls[threadIdx.x] = v;
  __syncthreads();
  for (int off=1; off<256; off<<=1){
    int t = (threadIdx.x >= off) ? ls[threadIdx.x-off] : 0;
    __syncthreads();
    ls[threadIdx.x] += t;
    __syncthreads();
  }
  int incl = ls[threadIdx.x];
  if (i < N_NODES) ROFF[i] = incl - v;
  if (threadIdx.x == 255) PART[blockIdx.x] = incl;
}
__global__ __launch_bounds__(512) void k_scan_b(int* __restrict__ PART){
  __shared__ int ls[512];
  int v = (threadIdx.x < SCAN_BLKS) ? PART[threadIdx.x] : 0;
  ls[threadIdx.x] = v;
  __syncthreads();
  for (int off=1; off<512; off<<=1){
    int t = (threadIdx.x >= off) ? ls[threadIdx.x-off] : 0;
    __syncthreads();
    ls[threadIdx.x] += t;
    __syncthreads();
  }
  if (threadIdx.x < SCAN_BLKS) PART[threadIdx.x] = ls[threadIdx.x] - v;
}
// ---- compacted scatter: iterate live-edge list ----
__global__ void k_scatterc(const int* __restrict__ L, const int* __restrict__ NLV, int which,
                           const int* __restrict__ par, const int* __restrict__ ROFF,
                           const int* __restrict__ PART, int* __restrict__ CUR,
                           int* __restrict__ EIDX){
  int j = blockIdx.x*256 + threadIdx.x;
  if (j >= NLV[which]) return;
  int e = L[j];
  int p = par[e];
  int pos = ROFF[p] + PART[p>>8] + atomicAdd(&CUR[p], 1);
  EIDX[pos] = e;
}

// ---- per-parent softmax + Householder aggregate; unroll-2 for MLP ----
__device__ __forceinline__ void agg_edge(int eid, float a, int lane,
    const int* __restrict__ chi, const int* __restrict__ relI,
    const float* __restrict__ DK,
    const unsigned short* __restrict__ Vh, const unsigned short* __restrict__ Xe,
    float acc[5]){
  float s2 = 2.f*DK[eid]*a;
  int y = chi[eid], r = relI[eid];
  const unsigned short* vr = Vh + (size_t)r*D;
  const unsigned short* ey = Xe + (size_t)y*320;
  #pragma unroll
  for (int q=0;q<4;++q){
    int d = lane + 64*q;
    acc[q] += b2f(ey[d])*a - s2*b2f(vr[d]);
  }
  if (lane < 44){
    int d = lane + 256;
    acc[4] += b2f(ey[d])*a - s2*b2f(vr[d]);
  }
}
__device__ __forceinline__ void agg_edge2(int eA, float aA, int eB, float aB, int lane,
    const int* __restrict__ chi, const int* __restrict__ relI,
    const float* __restrict__ DK,
    const unsigned short* __restrict__ Vh, const unsigned short* __restrict__ Xe,
    float acc[5]){
  float sA = 2.f*DK[eA]*aA, sB = 2.f*DK[eB]*aB;
  int yA = chi[eA], rA = relI[eA];
  int yB = chi[eB], rB = relI[eB];
  const unsigned short* vA = Vh + (size_t)rA*D;
  const unsigned short* eyA = Xe + (size_t)yA*320;
  const unsigned short* vB = Vh + (size_t)rB*D;
  const unsigned short* eyB = Xe + (size_t)yB*320;
  #pragma unroll
  for (int q=0;q<4;++q){
    int d = lane + 64*q;
    float e1 = b2f(eyA[d]), v1 = b2f(vA[d]);
    float e2 = b2f(eyB[d]), v2 = b2f(vB[d]);
    acc[q] += e1*aA - sA*v1;
    acc[q] += e2*aB - sB*v2;
  }
  if (lane < 44){
    int d = lane + 256;
    float e1 = b2f(eyA[d]), v1 = b2f(vA[d]);
    float e2 = b2f(eyB[d]), v2 = b2f(vB[d]);
    acc[4] += e1*aA - sA*v1;
    acc[4] += e2*aB - sB*v2;
  }
}
__device__ __forceinline__ void agg_bucket(int p, int lane,
    const int* __restrict__ ROFF, const int* __restrict__ PART, const int* __restrict__ CNT,
    const int* __restrict__ EIDX, const float* __restrict__ BBUF, const float* __restrict__ DK,
    const int* __restrict__ chi, const int* __restrict__ relI,
    const unsigned short* __restrict__ Vh, const unsigned short* __restrict__ Xe,
    float acc[5]){
  int cnt = CNT[p];
  if (cnt <= 0) return;
  int base = ROFF[p] + PART[p>>8];
  if (cnt <= 64){
    float bl = (lane < cnt) ? BBUF[EIDX[base+lane]] : -1e30f;
    float m = bl;
    #pragma unroll
    for (int msk=32; msk>=1; msk>>=1) m = fmaxf(m, __shfl_xor(m, msk));
    float el = (lane < cnt) ? __expf(bl - m) : 0.f;
    float s = wred(el);
    float inv = 1.f / fmaxf(s, 1e-10f);
    int i = 0;
    for (; i+1 < cnt; i += 2){
      int eA = EIDX[base+i], eB = EIDX[base+i+1];
      float aA = __shfl(el, i)*inv, aB = __shfl(el, i+1)*inv;
      agg_edge2(eA, aA, eB, aB, lane, chi, relI, DK, Vh, Xe, acc);
    }
    if (i < cnt){
      int eA = EIDX[base+i];
      agg_edge(eA, __shfl(el, i)*inv, lane, chi, relI, DK, Vh, Xe, acc);
    }
  } else {
    float m = -1e30f;
    for (int i=0;i<cnt;++i) m = fmaxf(m, BBUF[EIDX[base+i]]);
    float s = 0.f;
    for (int i=0;i<cnt;++i) s += __expf(BBUF[EIDX[base+i]] - m);
    float inv = 1.f / fmaxf(s, 1e-10f);
    int i = 0;
    for (; i+1 < cnt; i += 2){
      int eA = EIDX[base+i], eB = EIDX[base+i+1];
      float aA = __expf(BBUF[eA]-m)*inv, aB = __expf(BBUF[eB]-m)*inv;
      agg_edge2(eA, aA, eB, aB, lane, chi, relI, DK, Vh, Xe, acc);
    }
    if (i < cnt){
      int eA = EIDX[base+i];
      agg_edge(eA, __expf(BBUF[eA]-m)*inv, lane, chi, relI, DK, Vh, Xe, acc);
    }
  }
}

// ---- level-2 (compacted): one wave per needed parent from NDL ----
__global__ __launch_bounds__(256) void k_agg2(const int* __restrict__ ROFF, const int* __restrict__ PART,
    const int* __restrict__ CNT, const int* __restrict__ EIDX,
    const float* __restrict__ BBUF, const float* __restrict__ DK,
    const int* __restrict__ chi, const int* __restrict__ relI,
    const unsigned short* __restrict__ Vh, const unsigned short* __restrict__ Xe,
    const int* __restrict__ NDL, const int* __restrict__ NLV,
    unsigned short* __restrict__ Xo){
  int nlv = NLV[2];
  int idx = (blockIdx.x*256 + threadIdx.x) >> 6;
  if (idx >= nlv) return;
  int lane = threadIdx.x & 63;
  int p = NDL[idx];
  float acc[5] = {0.f,0.f,0.f,0.f,0.f};
  agg_bucket(p, lane, ROFF, PART, CNT, EIDX, BBUF, DK, chi, relI, Vh, Xe, acc);
  const unsigned short* in = Xe + (size_t)p*320;
  unsigned short* op = Xo + (size_t)p*320;
  #pragma unroll
  for (int q=0;q<4;++q){
    int d = lane + 64*q;
    op[d] = f2b(leaky(b2f(in[d]) + acc[q]));
  }
  {
    int d = lane + 256;
    unsigned short o = 0;
    if (lane < 44) o = f2b(leaky(b2f(in[d]) + acc[4]));
    op[d] = o;
  }
}

// ---- level-1: one wave per OUTPUT (8192); writes d_out directly ----
__global__ __launch_bounds__(256) void k_aggout(const int* __restrict__ ro,
    const int* __restrict__ ROFF, const int* __restrict__ PART,
    const int* __restrict__ CNT, const int* __restrict__ EIDX,
    const float* __restrict__ BBUF, const float* __restrict__ DK,
    const int* __restrict__ chi, const int* __restrict__ relI,
    const unsigned short* __restrict__ Vh, const unsigned short* __restrict__ Xe,
    float* __restrict__ out){
  int lane = threadIdx.x & 63;
  int o = (blockIdx.x*256 + threadIdx.x) >> 6;
  if (o >= NB) return;
  int p = ro[o];
  float acc[5] = {0.f,0.f,0.f,0.f,0.f};
  agg_bucket(p, lane, ROFF, PART, CNT, EIDX, BBUF, DK, chi, relI, Vh, Xe, acc);
  const unsigned short* in = Xe + (size_t)p*320;
  float* op = out + (size_t)o*D;
  #pragma unroll
  for (int q=0;q<4;++q){
    int d = lane + 64*q;
    op[d] = leaky(b2f(in[d]) + acc[q]);
  }
  if (lane < 44){
    int d = lane + 256;
    op[d] = leaky(b2f(in[d]) + acc[4]);
  }
}

extern "C" void kernel_launch(void* const* d_in, const int* in_sizes, int n_in,
                              void* d_out, int out_size, void* d_ws, size_t ws_size,
                              hipStream_t stream){
  const float* node = (const float*)d_in[0];
  const float* relT = (const float*)d_in[1];
  const float* W    = (const float*)d_in[2];
  const float* watt = (const float*)d_in[3];
  const int* par2 = (const int*)d_in[4];
  const int* chi2 = (const int*)d_in[5];
  const int* roo2 = (const int*)d_in[6];
  const int* rel2i = (const int*)d_in[7];
  const int* relrp2 = (const int*)d_in[8];
  const int* par1 = (const int*)d_in[9];
  const int* chi1 = (const int*)d_in[10];
  const int* roo1 = (const int*)d_in[11];
  const int* rel1i = (const int*)d_in[12];
  const int* roout = (const int*)d_in[13];

  char* w = (char*)d_ws;
  size_t off = 0;
  auto alloc = [&](size_t bytes)->void*{ void* p = w + off; off += (bytes + 255) & ~(size_t)255; return p; };
  unsigned short* Gh = (unsigned short*)alloc((size_t)N_NODES*RD*2);
  float* P    = (float*)alloc((size_t)N_NODES*4*4);
  unsigned short* Vh = (unsigned short*)alloc((size_t)NREL*D*2);
  float* RINV = (float*)alloc(NREL*4);
  float* RVW1 = (float*)alloc(NREL*4);
  float* RVW2 = (float*)alloc(NREL*4);
  float* BBUF = (float*)alloc((size_t)E2*4);
  float* DKb  = (float*)alloc((size_t)E2*4);
  unsigned short* Xb  = (unsigned short*)alloc((size_t)NPAD*320*2);
  unsigned short* Xb2 = (unsigned short*)alloc((size_t)NPAD*320*2);
  unsigned short* Bt  = (unsigned short*)alloc((size_t)112*320*2);
  unsigned short* MbT = (unsigned short*)alloc((size_t)112*128*2);
  unsigned short* WtB = (unsigned short*)alloc((size_t)304*128*2);
  unsigned short* Rb  = (unsigned short*)alloc((size_t)1024*128*2);
  int* FLAGS = (int*)alloc((size_t)7*N_NODES*4);   // FRO,ND2,NDA,CNTa,CURa,CNTb,CURb contiguous
  int* FRO  = FLAGS;
  int* ND2  = FLAGS + (size_t)N_NODES;
  int* NDA  = FLAGS + (size_t)2*N_NODES;
  int* CNTa = FLAGS + (size_t)3*N_NODES;
  int* CURa = FLAGS + (size_t)4*N_NODES;
  int* CNTb = FLAGS + (size_t)5*N_NODES;
  int* CURb = FLAGS + (size_t)6*N_NODES;
  int* ROFF = (int*)alloc((size_t)N_NODES*4);
  int* PART = (int*)alloc(512*4);
  int* EIDX = (int*)alloc((size_t)E2*4);
  int* L2L  = (int*)alloc((size_t)E2*4);
  int* L1L  = (int*)alloc((size_t)E1*4);
  int* NDL  = (int*)alloc((size_t)N_NODES*4);
  int* NAL  = (int*)alloc((size_t)N_NODES*4);
  int* NLV  = (int*)alloc(256);
  ull* MSK  = (ull*)alloc((size_t)4*NWAVES*8);
  int* BC   = (int*)alloc((size_t)4*NBLKC*4);
  int* BOFF = (int*)alloc((size_t)4*NBLKC*4);

  // backward-slice flags + scan-based compaction (index-only dependency, no global atomics)
  hipMemsetAsync(FLAGS, 0, (size_t)7*N_NODES*4, stream);
  k_flag<<<dim3((NB+255)/256), dim3(256), 0, stream>>>(roout, FRO, ND2);
  k_need<<<dim3((E1+255)/256), dim3(256), 0, stream>>>(par1, chi1, roo1, FRO, ND2);
  k_need2<<<dim3(NBLKC), dim3(256), 0, stream>>>(par2, chi2, roo2, ND2, NDA);
  k_cnt4<<<dim3(NBLKC), dim3(256), 0, stream>>>(par2, par1, FRO, ND2, NDA, MSK, BC);
  k_scanblk<<<dim3(4), dim3(1024), 0, stream>>>(BC, BOFF, NLV);
  k_fill4<<<dim3(NBLKC), dim3(256), 0, stream>>>(MSK, BOFF, L2L, L1L, NDL, NAL);

  // constants
  k_prepAll<<<dim3(412), dim3(256), 0, stream>>>(W, watt, relT, Bt, WtB, Rb, MbT);
  k_relmm<<<dim3(16), dim3(256), 0, stream>>>(Rb, WtB, watt, Vh, RINV, RVW1, RVW2);

  // ---------- level 2 (restricted to NAL nodes) ----------
  k_casti<<<dim3(2048), dim3(256), 0, stream>>>(node, NAL, NLV, Xb);
  k_nodetab2i<<<dim3((N_NODES+127)/128), dim3(256), 0, stream>>>(Xb, Bt, NAL, NLV, 3, Gh, P);
  k_pass1_l2c<<<dim3(E2/64), dim3(256), 0, stream>>>(relT, rel2i, relrp2, par2, chi2, roo2,
                                                     Gh, P, MbT, RINV, RVW2, L2L, NLV, BBUF, DKb, CNTa);
  k_scan_a<<<dim3(SCAN_BLKS), dim3(256), 0, stream>>>(CNTa, ROFF, PART);
  k_scan_b<<<dim3(1), dim3(512), 0, stream>>>(PART);
  k_scatterc<<<dim3((E2+255)/256), dim3(256), 0, stream>>>(L2L, NLV, 0, par2, ROFF, PART, CURa, EIDX);
  k_agg2<<<dim3((N_NODES+3)/4), dim3(256), 0, stream>>>(ROFF, PART, CNTa, EIDX, BBUF, DKb,
                                                        chi2, rel2i, Vh, Xb, NDL, NLV, Xb2);

  // ---------- level 1 ----------
  k_nodetab2i<<<dim3((N_NODES+127)/128), dim3(256), 0, stream>>>(Xb2, Bt, NDL, NLV, 2, Gh, P);
  k_pass1_l1c<<<dim3((E1+3)/4), dim3(256), 0, stream>>>(relT, rel1i, par1, chi1, roo1,
                                                        Gh, P, RINV, RVW1, RVW2, L1L, NLV, BBUF, DKb, CNTb);
  k_scan_a<<<dim3(SCAN_BLKS), dim3(256), 0, stream>>>(CNTb, ROFF, PART);
  k_scan_b<<<dim3(1), dim3(512), 0, stream>>>(PART);
  k_scatterc<<<dim3((E1+255)/256), dim3(256), 0, stream>>>(L1L, NLV, 1, par1, ROFF, PART, CURb, EIDX);
  k_aggout<<<dim3((NB+3)/4), dim3(256), 0, stream>>>(roout, ROFF, PART, CNTb, EIDX, BBUF, DKb,
                                                     chi1, rel1i, Vh, Xb2, (float*)d_out);
}